// Round 1
// baseline (1221.629 us; speedup 1.0000x reference)
//
#include <hip/hip_runtime.h>
#include <math.h>

typedef unsigned short u16;
typedef __bf16 v8bf __attribute__((ext_vector_type(8)));
typedef float   v4f  __attribute__((ext_vector_type(4)));

#define T_SEQ 2048
#define HID   5120
#define NH    16
#define DN    128
#define DR    64
#define DV    128
#define QL    1536
#define KVL   512
#define QKV_N (QL + KVL + DR)    // 2112
#define QB_N  (NH * (DN + DR))   // 3072
#define KVB_N (NH * (DN + DV))   // 4096
#define KFULL (KVL + DR)         // 576
#define OD    (NH * DV)          // 2048
#define KTT_LD 2080              // ktT leading dim (2048 + 32 pad: breaks 4KB aliasing)
#define SCALE_C 0.07216878364870322f       // (DN+DR)^-0.5
#define ROPE_K  0.28782313662425576f       // ln(10000)/32

__device__ __forceinline__ u16 f2b(float f) {
    unsigned int u = __float_as_uint(f);
    return (u16)((u + 0x7fffu + ((u >> 16) & 1u)) >> 16);
}

#if __has_builtin(__builtin_amdgcn_global_load_lds)
#define ASYNC_CP16(gp, lp) __builtin_amdgcn_global_load_lds( \
    (__attribute__((address_space(1))) void*)(gp),           \
    (__attribute__((address_space(3))) void*)(lp), 16, 0, 0)
#else
#define ASYNC_CP16(gp, lp) do { *(uint4*)(lp) = *(const uint4*)(gp); } while (0)
#endif

// ---------------------------------------------------------------------------
// f32 -> bf16 elementwise (n4 = count/4)
// ---------------------------------------------------------------------------
__global__ __launch_bounds__(256) void cvt_bf16(
    const float* __restrict__ in, u16* __restrict__ out, int n4)
{
    int i = blockIdx.x * 256 + threadIdx.x;
    if (i < n4) {
        float4 v = ((const float4*)in)[i];
        ushort4 o;
        o.x = f2b(v.x); o.y = f2b(v.y); o.z = f2b(v.z); o.w = f2b(v.w);
        ((ushort4*)out)[i] = o;
    }
}

// ---------------------------------------------------------------------------
// Transpose+convert: out[n][k] (bf16, row stride Kd) = in[k][col0+z*zcol+n] (f32)
// grid: (Kd/32, Nd/32, Z); 256 threads; 32x32 tiles.
// ---------------------------------------------------------------------------
__global__ __launch_bounds__(256) void transcvt(
    const float* __restrict__ in, u16* __restrict__ out,
    int ldin, int col0, int zcol, long out_z, int Kd)
{
    __shared__ u16 tile[32][33];
    const int bk = blockIdx.x * 32, bn = blockIdx.y * 32, z = blockIdx.z;
    const int r = threadIdx.x >> 3, cg = (threadIdx.x & 7) * 4;
    const float4 v = *(const float4*)(in + (size_t)(bk + r) * ldin + col0 + (size_t)z * zcol + bn + cg);
    tile[r][cg + 0] = f2b(v.x); tile[r][cg + 1] = f2b(v.y);
    tile[r][cg + 2] = f2b(v.z); tile[r][cg + 3] = f2b(v.w);
    __syncthreads();
    ushort4 o;
    o.x = tile[cg + 0][r]; o.y = tile[cg + 1][r];
    o.z = tile[cg + 2][r]; o.w = tile[cg + 3][r];
    *(ushort4*)(out + (size_t)z * out_z + (size_t)(bn + r) * Kd + bk + cg) = o;
}

// ---------------------------------------------------------------------------
// bf16 MFMA GEMM (m97-style): C(f32, MxN) = A(bf16 MxK) * Bt(bf16 NxK)^T
// 128x128 tile, BK=32, 256 thr, 4 waves each 64x64 (4x4 x 16x16x32 frags).
// M%128==0, K%32==0; N guarded on store (Bt rows must be allocated to 128-mult).
// ---------------------------------------------------------------------------
__global__ __launch_bounds__(256, 2) void gemm_bt(
    const u16* __restrict__ A, const u16* __restrict__ Bt,
    float* __restrict__ C, int M, int N, int K)
{
    __shared__ u16 As[128 * 32], Bs[128 * 32];
    const int tid = threadIdx.x, lane = tid & 63, wave = tid >> 6;
    const int g = lane >> 4, l15 = lane & 15;
    const int bm = blockIdx.y * 128, bn = blockIdx.x * 128;
    const int wm = (wave & 1) * 64, wn = (wave >> 1) * 64;
    const int srow = tid >> 2, skq = (tid & 3) * 8;   // staging: row 0..63, k-chunk
    v4f acc[4][4];
#pragma unroll
    for (int i = 0; i < 4; ++i)
#pragma unroll
        for (int j = 0; j < 4; ++j) acc[i][j] = (v4f){0.f, 0.f, 0.f, 0.f};

    for (int k0 = 0; k0 < K; k0 += 32) {
        ASYNC_CP16(A  + (size_t)(bm + srow) * K + k0 + skq,      &As[tid * 8]);
        ASYNC_CP16(A  + (size_t)(bm + 64 + srow) * K + k0 + skq, &As[2048 + tid * 8]);
        ASYNC_CP16(Bt + (size_t)(bn + srow) * K + k0 + skq,      &Bs[tid * 8]);
        ASYNC_CP16(Bt + (size_t)(bn + 64 + srow) * K + k0 + skq, &Bs[2048 + tid * 8]);
        __syncthreads();
        v8bf af[4], bq[4];
#pragma unroll
        for (int mi = 0; mi < 4; ++mi) af[mi] = *(const v8bf*)&As[(wm + mi * 16 + l15) * 32 + g * 8];
#pragma unroll
        for (int ni = 0; ni < 4; ++ni) bq[ni] = *(const v8bf*)&Bs[(wn + ni * 16 + l15) * 32 + g * 8];
#pragma unroll
        for (int mi = 0; mi < 4; ++mi)
#pragma unroll
            for (int ni = 0; ni < 4; ++ni)
                acc[mi][ni] = __builtin_amdgcn_mfma_f32_16x16x32_bf16(af[mi], bq[ni], acc[mi][ni], 0, 0, 0);
        __syncthreads();
    }
#pragma unroll
    for (int mi = 0; mi < 4; ++mi)
#pragma unroll
        for (int ni = 0; ni < 4; ++ni) {
            const int col = bn + wn + ni * 16 + l15;
            if (col < N) {
#pragma unroll
                for (int r = 0; r < 4; ++r)
                    C[(size_t)(bm + wm + mi * 16 + g * 4 + r) * N + col] = acc[mi][ni][r];
            }
        }
}

// ---------------------------------------------------------------------------
// Batched per-head w_vc GEMM: o_mid[t][h*128+v] (bf16) = o_lat_h(2048x512) @ wvcT_h(128x512)^T
// grid (16, NH).
// ---------------------------------------------------------------------------
__global__ __launch_bounds__(256, 2) void gemm_vc(
    const u16* __restrict__ o_lat, const u16* __restrict__ wvcT,
    u16* __restrict__ o_mid)
{
    __shared__ u16 As[128 * 32], Bs[128 * 32];
    const int tid = threadIdx.x, lane = tid & 63, wave = tid >> 6;
    const int g = lane >> 4, l15 = lane & 15;
    const int h = blockIdx.y;
    const int bm = blockIdx.x * 128;
    const u16* A  = o_lat + (size_t)h * T_SEQ * 512;
    const u16* Bt = wvcT + (size_t)h * 128 * 512;
    const int wm = (wave & 1) * 64, wn = (wave >> 1) * 64;
    const int srow = tid >> 2, skq = (tid & 3) * 8;
    v4f acc[4][4];
#pragma unroll
    for (int i = 0; i < 4; ++i)
#pragma unroll
        for (int j = 0; j < 4; ++j) acc[i][j] = (v4f){0.f, 0.f, 0.f, 0.f};

    for (int k0 = 0; k0 < 512; k0 += 32) {
        ASYNC_CP16(A  + (size_t)(bm + srow) * 512 + k0 + skq,      &As[tid * 8]);
        ASYNC_CP16(A  + (size_t)(bm + 64 + srow) * 512 + k0 + skq, &As[2048 + tid * 8]);
        ASYNC_CP16(Bt + (size_t)(srow) * 512 + k0 + skq,           &Bs[tid * 8]);
        ASYNC_CP16(Bt + (size_t)(64 + srow) * 512 + k0 + skq,      &Bs[2048 + tid * 8]);
        __syncthreads();
        v8bf af[4], bq[4];
#pragma unroll
        for (int mi = 0; mi < 4; ++mi) af[mi] = *(const v8bf*)&As[(wm + mi * 16 + l15) * 32 + g * 8];
#pragma unroll
        for (int ni = 0; ni < 4; ++ni) bq[ni] = *(const v8bf*)&Bs[(wn + ni * 16 + l15) * 32 + g * 8];
#pragma unroll
        for (int mi = 0; mi < 4; ++mi)
#pragma unroll
            for (int ni = 0; ni < 4; ++ni)
                acc[mi][ni] = __builtin_amdgcn_mfma_f32_16x16x32_bf16(af[mi], bq[ni], acc[mi][ni], 0, 0, 0);
        __syncthreads();
    }
#pragma unroll
    for (int mi = 0; mi < 4; ++mi)
#pragma unroll
        for (int ni = 0; ni < 4; ++ni)
#pragma unroll
            for (int r = 0; r < 4; ++r)
                o_mid[(size_t)(bm + wm + mi * 16 + g * 4 + r) * OD + h * 128 + wn + ni * 16 + l15] =
                    f2b(acc[mi][ni][r]);
}

// ---------------------------------------------------------------------------
// Fused rmsnorms + k_pe rope. Reads qkv f32; writes qanorm bf16, kfull bf16,
// ktT bf16 (kv-latent transposed, [512][KTT_LD]). One block per row t.
// ---------------------------------------------------------------------------
__global__ __launch_bounds__(256) void norm_rope_kernel(
    const float* __restrict__ qkv, const float* __restrict__ qa_w,
    const float* __restrict__ kva_w, const int* __restrict__ positions,
    u16* __restrict__ qanorm, u16* __restrict__ kfull, u16* __restrict__ ktT)
{
    const int t = blockIdx.x, tid = threadIdx.x;
    const float* row = qkv + (size_t)t * QKV_N;
    float sq = 0.f, skv = 0.f;
    for (int i = tid; i < QL; i += 256)  { const float v = row[i];      sq  = fmaf(v, v, sq); }
    for (int i = tid; i < KVL; i += 256) { const float v = row[QL + i]; skv = fmaf(v, v, skv); }
#pragma unroll
    for (int off = 32; off >= 1; off >>= 1) {
        sq  += __shfl_down(sq, off, 64);
        skv += __shfl_down(skv, off, 64);
    }
    __shared__ float red[2][4];
    __shared__ float rs[2];
    const int wv = tid >> 6;
    if ((tid & 63) == 0) { red[0][wv] = sq; red[1][wv] = skv; }
    __syncthreads();
    if (tid == 0) {
        const float a = red[0][0] + red[0][1] + red[0][2] + red[0][3];
        const float b = red[1][0] + red[1][1] + red[1][2] + red[1][3];
        rs[0] = rsqrtf(a / (float)QL + 1e-6f);
        rs[1] = rsqrtf(b / (float)KVL + 1e-6f);
    }
    __syncthreads();
    const float rq = rs[0], rkv = rs[1];
    for (int i = tid; i < QL; i += 256)
        qanorm[(size_t)t * QL + i] = f2b(row[i] * rq * qa_w[i]);
    for (int i = tid; i < KVL; i += 256) {
        const u16 b = f2b(row[QL + i] * rkv * kva_w[i]);
        kfull[(size_t)t * KFULL + i] = b;
        ktT[(size_t)i * KTT_LD + t] = b;
    }
    if (tid < 32) {
        const float pos = (float)positions[t];
        const float inv = __expf(-(float)tid * ROPE_K);
        float s, c;
        __sincosf(pos * inv, &s, &c);
        const float x1 = row[QL + KVL + 2 * tid];
        const float x2 = row[QL + KVL + 2 * tid + 1];
        kfull[(size_t)t * KFULL + KVL + 2 * tid]     = f2b(x1 * c - x2 * s);
        kfull[(size_t)t * KFULL + KVL + 2 * tid + 1] = f2b(x2 * c + x1 * s);
    }
}

// ---------------------------------------------------------------------------
// Absorbed q_nope (f32 VALU), output bf16 pre-scaled: qf[h][t][l]
// ---------------------------------------------------------------------------
__global__ __launch_bounds__(256) void gemm_qnope_kernel(
    const float* __restrict__ q, const float* __restrict__ w_kvb,
    u16* __restrict__ qf)
{
    const int h = blockIdx.z;
    const int bn = blockIdx.x * 64;   // l
    const int bm = blockIdx.y * 64;   // t
    const int tid = threadIdx.x;
    __shared__ float As[16][68];
    __shared__ float Bs[16][68];
    const int tx = tid & 15, ty = tid >> 4;
    float acc[4][4];
#pragma unroll
    for (int i = 0; i < 4; ++i)
#pragma unroll
        for (int j = 0; j < 4; ++j) acc[i][j] = 0.f;

    const float* Abase = q + (size_t)bm * QB_N + h * (DN + DR);
    const float* Bbase = w_kvb + (size_t)bn * KVB_N + h * (DN + DV);
    const int row = tid >> 2, kq = (tid & 3) << 2;
    for (int k0 = 0; k0 < DN; k0 += 16) {
        {
            const float4 a4 = *(const float4*)(Abase + (size_t)row * QB_N + k0 + kq);
            As[kq + 0][row] = a4.x; As[kq + 1][row] = a4.y;
            As[kq + 2][row] = a4.z; As[kq + 3][row] = a4.w;
            const float4 b4 = *(const float4*)(Bbase + (size_t)row * KVB_N + k0 + kq);
            Bs[kq + 0][row] = b4.x; Bs[kq + 1][row] = b4.y;
            Bs[kq + 2][row] = b4.z; Bs[kq + 3][row] = b4.w;
        }
        __syncthreads();
#pragma unroll
        for (int kk = 0; kk < 16; ++kk) {
            float a[4], b[4];
            *(float4*)a = *(const float4*)(&As[kk][ty * 4]);
            *(float4*)b = *(const float4*)(&Bs[kk][tx * 4]);
#pragma unroll
            for (int i = 0; i < 4; ++i)
#pragma unroll
                for (int j = 0; j < 4; ++j)
                    acc[i][j] = fmaf(a[i], b[j], acc[i][j]);
        }
        __syncthreads();
    }
#pragma unroll
    for (int i = 0; i < 4; ++i)
#pragma unroll
        for (int j = 0; j < 4; ++j)
            qf[((size_t)h * T_SEQ + bm + ty * 4 + i) * KFULL + bn + tx * 4 + j] =
                f2b(acc[i][j] * SCALE_C);
}

// ---------------------------------------------------------------------------
// RoPE on q_pe -> qf[h][t][512:576] bf16, pre-scaled.
// ---------------------------------------------------------------------------
__global__ __launch_bounds__(256) void rope_qpe_kernel(
    const float* __restrict__ q, const int* __restrict__ positions,
    u16* __restrict__ qf)
{
    const int t = blockIdx.x, tid = threadIdx.x;
    const float pos = (float)positions[t];
    for (int p = tid; p < NH * 32; p += 256) {
        const int h = p >> 5, i = p & 31;
        const float inv = __expf(-(float)i * ROPE_K);
        float s, c;
        __sincosf(pos * inv, &s, &c);
        const float* src = q + (size_t)t * QB_N + h * (DN + DR) + DN;
        u16* dst = qf + ((size_t)h * T_SEQ + t) * KFULL + KVL;
        const float x1 = src[2 * i], x2 = src[2 * i + 1];
        dst[2 * i]     = f2b(SCALE_C * (x1 * c - x2 * s));
        dst[2 * i + 1] = f2b(SCALE_C * (x2 * c + x1 * s));
    }
}

// ---------------------------------------------------------------------------
// Barrier-free per-wave MFMA flash attention.
// Block = 128 thr = 2 independent waves; each wave owns one 16-row q-tile of
// one head (tile = blockIdx.x*2 + wave, 0..127). Grid (64, NH) = 1024 blocks
// = 4 blocks/CU resident (LDS 4x39.4KB = 157.7KB), 8 waves/CU.
// K fragments read directly from kfull (L2-resident, 2.3MB); V fragments
// directly from ktT (2.1MB, LD padded to 2080 to break 4KB set-aliasing).
// Q staged once per wave into XOR-swizzled LDS (conflict-free ds_read_b128).
// P tile lives in a per-wave LDS slice (intra-wave lgkmcnt ordering only).
// No __syncthreads anywhere.
// ---------------------------------------------------------------------------
__global__ __launch_bounds__(128, 2) void attn_mfma(
    const u16* __restrict__ qf, const u16* __restrict__ kfull,
    const u16* __restrict__ ktT, u16* __restrict__ o_lat)
{
    __shared__ u16 Qs[2][16 * 576];     // per-wave, XOR-swizzled rows (18432B each)
    __shared__ u16 pt_s[2][16 * 40];    // per-wave P tile, row stride 40
    const int h = blockIdx.y;
    const int tid = threadIdx.x, lane = tid & 63, wave = tid >> 6;
    const int tile = blockIdx.x * 2 + wave;   // 16-row q tile, 0..127
    const int qt0 = tile * 16;
    const int g = lane >> 4, l15 = lane & 15;

    // ---- stage this wave's Q tile (16 x 576 bf16) into swizzled LDS ----
    {
        const int r = lane >> 2, c4 = lane & 3;           // 4 lanes per row
        const u16* src = qf + ((size_t)h * T_SEQ + qt0 + r) * KFULL;
        char* dst = (char*)Qs[wave];
#pragma unroll
        for (int i = 0; i < 18; ++i) {
            const int c16 = c4 + i * 4;                   // 16B chunk 0..71
            *(uint4*)(dst + ((r * 1152 + c16 * 16) ^ ((r & 7) << 4))) =
                *(const uint4*)(src + c16 * 8);
        }
    }
    asm volatile("s_waitcnt lgkmcnt(0)" ::: "memory");

    v4f acc[32];
#pragma unroll
    for (int v = 0; v < 32; ++v) acc[v] = (v4f){0.f, 0.f, 0.f, 0.f};
    float mr[4] = {-1e30f, -1e30f, -1e30f, -1e30f};
    float lr[4] = {0.f, 0.f, 0.f, 0.f};

    const char* qsw = (const char*)Qs[wave];
    const int nk = (tile + 2) >> 1;     // number of 32-key tiles (exact causal)
    for (int kt = 0; kt < nk; ++kt) {
        const int kt0 = kt * 32;
        // ---- S = Q K^T : K fragments straight from global (L1/L2) ----
        v4f s0 = (v4f){0.f, 0.f, 0.f, 0.f}, s1 = (v4f){0.f, 0.f, 0.f, 0.f};
        const u16* kp = kfull + (size_t)(kt0 + l15) * KFULL + g * 8;
#pragma unroll
        for (int c = 0; c < 18; ++c) {
            const v8bf aq = *(const v8bf*)(qsw +
                ((l15 * 1152 + (c * 4 + g) * 16) ^ ((l15 & 7) << 4)));
            const v8bf b0 = *(const v8bf*)(kp + c * 32);
            const v8bf b1 = *(const v8bf*)(kp + 16 * KFULL + c * 32);
            s0 = __builtin_amdgcn_mfma_f32_16x16x32_bf16(aq, b0, s0, 0, 0, 0);
            s1 = __builtin_amdgcn_mfma_f32_16x16x32_bf16(aq, b1, s1, 0, 0, 0);
        }
        // ---- online softmax (registers + shfl within 16-lane col group) ----
        const int qr = qt0 + g * 4;
        const int kc0 = kt0 + l15, kc1 = kt0 + 16 + l15;
        float alpha[4];
        int resc = 0;
#pragma unroll
        for (int r = 0; r < 4; ++r) {
            const float sv0 = (kc0 <= qr + r) ? s0[r] : -1e30f;
            const float sv1 = (kc1 <= qr + r) ? s1[r] : -1e30f;
            float v = fmaxf(sv0, sv1);
            v = fmaxf(v, __shfl_xor(v, 1, 64));
            v = fmaxf(v, __shfl_xor(v, 2, 64));
            v = fmaxf(v, __shfl_xor(v, 4, 64));
            v = fmaxf(v, __shfl_xor(v, 8, 64));
            const float mx = fmaxf(mr[r], v);
            alpha[r] = __expf(mr[r] - mx);
            resc |= (mx != mr[r]);
            const float p0 = __expf(sv0 - mx);
            const float p1 = __expf(sv1 - mx);
            pt_s[wave][(g * 4 + r) * 40 + l15]      = f2b(p0);
            pt_s[wave][(g * 4 + r) * 40 + 16 + l15] = f2b(p1);
            float s = p0 + p1;
            s += __shfl_xor(s, 1, 64);
            s += __shfl_xor(s, 2, 64);
            s += __shfl_xor(s, 4, 64);
            s += __shfl_xor(s, 8, 64);
            mr[r] = mx;
            lr[r] = lr[r] * alpha[r] + s;
        }
        // rescale O only when the running max actually grew (exact: alpha==1 else)
        if (__any(resc)) {
#pragma unroll
            for (int v = 0; v < 32; ++v) {
                acc[v][0] *= alpha[0]; acc[v][1] *= alpha[1];
                acc[v][2] *= alpha[2]; acc[v][3] *= alpha[3];
            }
        }
        asm volatile("s_waitcnt lgkmcnt(0)" ::: "memory");   // P writes visible (same wave)
        // ---- O += P V : V fragments straight from global ktT ----
        const v8bf pf = *(const v8bf*)(pt_s[wave] + l15 * 40 + g * 8);
        const u16* vp = ktT + kt0 + g * 8;
#pragma unroll
        for (int v = 0; v < 32; ++v) {
            const v8bf vb = *(const v8bf*)(vp + (size_t)(v * 16 + l15) * KTT_LD);
            acc[v] = __builtin_amdgcn_mfma_f32_16x16x32_bf16(pf, vb, acc[v], 0, 0, 0);
        }
    }
    // ---- normalize + store ----
    const float li0 = 1.f / lr[0], li1 = 1.f / lr[1], li2 = 1.f / lr[2], li3 = 1.f / lr[3];
    u16* op = o_lat + ((size_t)h * T_SEQ + qt0 + g * 4) * 512 + l15;
#pragma unroll
    for (int v = 0; v < 32; ++v) {
        op[0 * 512 + v * 16] = f2b(acc[v][0] * li0);
        op[1 * 512 + v * 16] = f2b(acc[v][1] * li1);
        op[2 * 512 + v * 16] = f2b(acc[v][2] * li2);
        op[3 * 512 + v * 16] = f2b(acc[v][3] * li3);
    }
}

// ---------------------------------------------------------------------------
extern "C" void kernel_launch(void* const* d_in, const int* in_sizes, int n_in,
                              void* d_out, int out_size, void* d_ws, size_t ws_size,
                              hipStream_t stream)
{
    const int*   positions = (const int*)d_in[0];
    const float* hs        = (const float*)d_in[1];
    const float* w_fused   = (const float*)d_in[2];
    const float* w_qb      = (const float*)d_in[3];
    const float* w_kvb     = (const float*)d_in[4];
    const float* w_o       = (const float*)d_in[5];
    const float* qa_w      = (const float*)d_in[6];
    const float* kva_w     = (const float*)d_in[7];
    float* out = (float*)d_out;
    char*  ws  = (char*)d_ws;

    // workspace layout (bytes), with phase-disjoint aliasing:
    // R0 (38,010,880): [wfT 2176x5120 bf16][wqbT 3072x1536][qanorm 2048x1536]  -> later o_lat 16x2048x512
    // R1 (17,301,504): qkv f32 2048x2112                                       -> later o_mid 2048x2048 bf16
    // R2 (25,165,824): hs_bf 2048x5120 bf16 -> qmat f32 2048x3072 -> woT 5120x2048 bf16
    // R3: wvcT 16x128x512 bf16 | R4: kfull bf16 | R5: ktT bf16 [512][2080] | R6: qf bf16
    char* R0 = ws;
    char* R1 = R0 + 38010880;
    char* R2 = R1 + 17301504;
    char* R3 = R2 + 25165824;
    char* R4 = R3 + 2097152;
    char* R5 = R4 + 2359296;
    char* R6 = R5 + 2162688;     // ktT now 512*2080*2 = 2,129,920 B; R6 end ~124.85MB (< proven 134.7MB)

    u16*   wfT    = (u16*)R0;
    u16*   wqbT   = (u16*)(R0 + 22282240);
    u16*   qanorm = (u16*)(R0 + 31719424);
    u16*   o_lat  = (u16*)R0;
    float* qkv    = (float*)R1;
    u16*   o_mid  = (u16*)R1;
    u16*   hs_bf  = (u16*)R2;
    float* qmat   = (float*)R2;
    u16*   woT    = (u16*)R2;
    u16*   wvcT   = (u16*)R3;
    u16*   kfull  = (u16*)R4;
    u16*   ktT    = (u16*)R5;
    u16*   qf     = (u16*)R6;

    // 1. convert hs -> bf16
    cvt_bf16<<<(T_SEQ * HID / 4 + 255) / 256, 256, 0, stream>>>(hs, hs_bf, T_SEQ * HID / 4);
    // 2. transpose-convert w_fused -> wfT [2112(pad2176)][5120]
    transcvt<<<dim3(HID / 32, QKV_N / 32, 1), 256, 0, stream>>>(w_fused, wfT, QKV_N, 0, 0, 0, HID);
    // 3. qkv = hs @ w_fused   (f32 out)
    gemm_bt<<<dim3((QKV_N + 127) / 128, T_SEQ / 128), 256, 0, stream>>>(
        hs_bf, wfT, qkv, T_SEQ, QKV_N, HID);
    // 4. transpose-convert w_qb -> wqbT [3072][1536]
    transcvt<<<dim3(QL / 32, QB_N / 32, 1), 256, 0, stream>>>(w_qb, wqbT, QB_N, 0, 0, 0, QL);
    // 5. rmsnorms + k_pe rope -> qanorm bf16, kfull bf16, ktT bf16
    norm_rope_kernel<<<T_SEQ, 256, 0, stream>>>(qkv, qa_w, kva_w, positions, qanorm, kfull, ktT);
    // 6. qmat = qanorm @ w_qb  (f32 out; overwrites hs_bf region)
    gemm_bt<<<dim3(QB_N / 128, T_SEQ / 128), 256, 0, stream>>>(
        qanorm, wqbT, qmat, T_SEQ, QB_N, QL);
    // 7. absorbed q_nope + q_pe rope -> qf bf16 (pre-scaled)
    gemm_qnope_kernel<<<dim3(KVL / 64, T_SEQ / 64, NH), 256, 0, stream>>>(qmat, w_kvb, qf);
    rope_qpe_kernel<<<T_SEQ, 256, 0, stream>>>(qmat, positions, qf);
    // 8. wvcT[h][v][l] from w_kvb
    transcvt<<<dim3(KVL / 32, DV / 32, NH), 256, 0, stream>>>(
        w_kvb, wvcT, KVB_N, DN, DN + DV, (long)DV * KVL, KVL);
    // 9. barrier-free per-wave MFMA flash attention -> o_lat bf16
    attn_mfma<<<dim3(64, NH), 128, 0, stream>>>(qf, kfull, ktT, o_lat);
    // 10. o_mid = per-head o_lat @ w_vc  (bf16 out; overwrites qkv)
    gemm_vc<<<dim3(T_SEQ / 128, NH), 256, 0, stream>>>(o_lat, wvcT, o_mid);
    // 11. transpose-convert w_o -> woT [5120][2048] (overwrites qmat)
    transcvt<<<dim3(OD / 32, HID / 32, 1), 256, 0, stream>>>(w_o, woT, HID, 0, 0, 0, OD);
    // 12. out = o_mid @ w_o  (f32 out)
    gemm_bt<<<dim3(HID / 128, T_SEQ / 128), 256, 0, stream>>>(
        o_mid, woT, out, T_SEQ, HID, OD);
}

// Round 2
// 1094.942 us; speedup vs baseline: 1.1157x; 1.1157x over previous
//
#include <hip/hip_runtime.h>
#include <math.h>

typedef unsigned short u16;
typedef __bf16 v8bf __attribute__((ext_vector_type(8)));
typedef float   v4f  __attribute__((ext_vector_type(4)));

#define T_SEQ 2048
#define HID   5120
#define NH    16
#define DN    128
#define DR    64
#define DV    128
#define QL    1536
#define KVL   512
#define QKV_N (QL + KVL + DR)    // 2112
#define QB_N  (NH * (DN + DR))   // 3072
#define KVB_N (NH * (DN + DV))   // 4096
#define KFULL (KVL + DR)         // 576
#define OD    (NH * DV)          // 2048
#define KTT_LD 2080              // ktT leading dim (2048 + 32 pad)
#define SCALE_C 0.07216878364870322f       // (DN+DR)^-0.5
#define ROPE_K  0.28782313662425576f       // ln(10000)/32

__device__ __forceinline__ u16 f2b(float f) {
    unsigned int u = __float_as_uint(f);
    return (u16)((u + 0x7fffu + ((u >> 16) & 1u)) >> 16);
}

#if __has_builtin(__builtin_amdgcn_global_load_lds)
#define ASYNC_CP16(gp, lp) __builtin_amdgcn_global_load_lds( \
    (__attribute__((address_space(1))) void*)(gp),           \
    (__attribute__((address_space(3))) void*)(lp), 16, 0, 0)
#else
#define ASYNC_CP16(gp, lp) do { *(uint4*)(lp) = *(const uint4*)(gp); } while (0)
#endif

// ---------------------------------------------------------------------------
// f32 -> bf16 elementwise (n4 = count/4)
// ---------------------------------------------------------------------------
__global__ __launch_bounds__(256) void cvt_bf16(
    const float* __restrict__ in, u16* __restrict__ out, int n4)
{
    int i = blockIdx.x * 256 + threadIdx.x;
    if (i < n4) {
        float4 v = ((const float4*)in)[i];
        ushort4 o;
        o.x = f2b(v.x); o.y = f2b(v.y); o.z = f2b(v.z); o.w = f2b(v.w);
        ((ushort4*)out)[i] = o;
    }
}

// ---------------------------------------------------------------------------
// Transpose+convert: out[n][k] (bf16, row stride Kd) = in[k][col0+z*zcol+n] (f32)
// grid: (Kd/32, Nd/32, Z); 256 threads; 32x32 tiles.
// ---------------------------------------------------------------------------
__global__ __launch_bounds__(256) void transcvt(
    const float* __restrict__ in, u16* __restrict__ out,
    int ldin, int col0, int zcol, long out_z, int Kd)
{
    __shared__ u16 tile[32][33];
    const int bk = blockIdx.x * 32, bn = blockIdx.y * 32, z = blockIdx.z;
    const int r = threadIdx.x >> 3, cg = (threadIdx.x & 7) * 4;
    const float4 v = *(const float4*)(in + (size_t)(bk + r) * ldin + col0 + (size_t)z * zcol + bn + cg);
    tile[r][cg + 0] = f2b(v.x); tile[r][cg + 1] = f2b(v.y);
    tile[r][cg + 2] = f2b(v.z); tile[r][cg + 3] = f2b(v.w);
    __syncthreads();
    ushort4 o;
    o.x = tile[cg + 0][r]; o.y = tile[cg + 1][r];
    o.z = tile[cg + 2][r]; o.w = tile[cg + 3][r];
    *(ushort4*)(out + (size_t)z * out_z + (size_t)(bn + r) * Kd + bk + cg) = o;
}

// ---------------------------------------------------------------------------
// bf16 MFMA GEMM (m97-style): C(f32, MxN) = A(bf16 MxK) * Bt(bf16 NxK)^T
// 128x128 tile, BK=32, 256 thr, 4 waves each 64x64 (4x4 x 16x16x32 frags).
// ---------------------------------------------------------------------------
__global__ __launch_bounds__(256, 2) void gemm_bt(
    const u16* __restrict__ A, const u16* __restrict__ Bt,
    float* __restrict__ C, int M, int N, int K)
{
    __shared__ u16 As[128 * 32], Bs[128 * 32];
    const int tid = threadIdx.x, lane = tid & 63, wave = tid >> 6;
    const int g = lane >> 4, l15 = lane & 15;
    const int bm = blockIdx.y * 128, bn = blockIdx.x * 128;
    const int wm = (wave & 1) * 64, wn = (wave >> 1) * 64;
    const int srow = tid >> 2, skq = (tid & 3) * 8;
    v4f acc[4][4];
#pragma unroll
    for (int i = 0; i < 4; ++i)
#pragma unroll
        for (int j = 0; j < 4; ++j) acc[i][j] = (v4f){0.f, 0.f, 0.f, 0.f};

    for (int k0 = 0; k0 < K; k0 += 32) {
        ASYNC_CP16(A  + (size_t)(bm + srow) * K + k0 + skq,      &As[tid * 8]);
        ASYNC_CP16(A  + (size_t)(bm + 64 + srow) * K + k0 + skq, &As[2048 + tid * 8]);
        ASYNC_CP16(Bt + (size_t)(bn + srow) * K + k0 + skq,      &Bs[tid * 8]);
        ASYNC_CP16(Bt + (size_t)(bn + 64 + srow) * K + k0 + skq, &Bs[2048 + tid * 8]);
        __syncthreads();
        v8bf af[4], bq[4];
#pragma unroll
        for (int mi = 0; mi < 4; ++mi) af[mi] = *(const v8bf*)&As[(wm + mi * 16 + l15) * 32 + g * 8];
#pragma unroll
        for (int ni = 0; ni < 4; ++ni) bq[ni] = *(const v8bf*)&Bs[(wn + ni * 16 + l15) * 32 + g * 8];
#pragma unroll
        for (int mi = 0; mi < 4; ++mi)
#pragma unroll
            for (int ni = 0; ni < 4; ++ni)
                acc[mi][ni] = __builtin_amdgcn_mfma_f32_16x16x32_bf16(af[mi], bq[ni], acc[mi][ni], 0, 0, 0);
        __syncthreads();
    }
#pragma unroll
    for (int mi = 0; mi < 4; ++mi)
#pragma unroll
        for (int ni = 0; ni < 4; ++ni) {
            const int col = bn + wn + ni * 16 + l15;
            if (col < N) {
#pragma unroll
                for (int r = 0; r < 4; ++r)
                    C[(size_t)(bm + wm + mi * 16 + g * 4 + r) * N + col] = acc[mi][ni][r];
            }
        }
}

// ---------------------------------------------------------------------------
// Batched per-head w_vc GEMM: o_mid[t][h*128+v] = o_lat_h(2048x512) @ wvcT_h(128x512)^T
// ---------------------------------------------------------------------------
__global__ __launch_bounds__(256, 2) void gemm_vc(
    const u16* __restrict__ o_lat, const u16* __restrict__ wvcT,
    u16* __restrict__ o_mid)
{
    __shared__ u16 As[128 * 32], Bs[128 * 32];
    const int tid = threadIdx.x, lane = tid & 63, wave = tid >> 6;
    const int g = lane >> 4, l15 = lane & 15;
    const int h = blockIdx.y;
    const int bm = blockIdx.x * 128;
    const u16* A  = o_lat + (size_t)h * T_SEQ * 512;
    const u16* Bt = wvcT + (size_t)h * 128 * 512;
    const int wm = (wave & 1) * 64, wn = (wave >> 1) * 64;
    const int srow = tid >> 2, skq = (tid & 3) * 8;
    v4f acc[4][4];
#pragma unroll
    for (int i = 0; i < 4; ++i)
#pragma unroll
        for (int j = 0; j < 4; ++j) acc[i][j] = (v4f){0.f, 0.f, 0.f, 0.f};

    for (int k0 = 0; k0 < 512; k0 += 32) {
        ASYNC_CP16(A  + (size_t)(bm + srow) * 512 + k0 + skq,      &As[tid * 8]);
        ASYNC_CP16(A  + (size_t)(bm + 64 + srow) * 512 + k0 + skq, &As[2048 + tid * 8]);
        ASYNC_CP16(Bt + (size_t)(srow) * 512 + k0 + skq,           &Bs[tid * 8]);
        ASYNC_CP16(Bt + (size_t)(64 + srow) * 512 + k0 + skq,      &Bs[2048 + tid * 8]);
        __syncthreads();
        v8bf af[4], bq[4];
#pragma unroll
        for (int mi = 0; mi < 4; ++mi) af[mi] = *(const v8bf*)&As[(wm + mi * 16 + l15) * 32 + g * 8];
#pragma unroll
        for (int ni = 0; ni < 4; ++ni) bq[ni] = *(const v8bf*)&Bs[(wn + ni * 16 + l15) * 32 + g * 8];
#pragma unroll
        for (int mi = 0; mi < 4; ++mi)
#pragma unroll
            for (int ni = 0; ni < 4; ++ni)
                acc[mi][ni] = __builtin_amdgcn_mfma_f32_16x16x32_bf16(af[mi], bq[ni], acc[mi][ni], 0, 0, 0);
        __syncthreads();
    }
#pragma unroll
    for (int mi = 0; mi < 4; ++mi)
#pragma unroll
        for (int ni = 0; ni < 4; ++ni)
#pragma unroll
            for (int r = 0; r < 4; ++r)
                o_mid[(size_t)(bm + wm + mi * 16 + g * 4 + r) * OD + h * 128 + wn + ni * 16 + l15] =
                    f2b(acc[mi][ni][r]);
}

// ---------------------------------------------------------------------------
// Fused rmsnorms + k_pe rope. Writes qanorm bf16, kfull bf16, ktT bf16 [512][KTT_LD].
// ---------------------------------------------------------------------------
__global__ __launch_bounds__(256) void norm_rope_kernel(
    const float* __restrict__ qkv, const float* __restrict__ qa_w,
    const float* __restrict__ kva_w, const int* __restrict__ positions,
    u16* __restrict__ qanorm, u16* __restrict__ kfull, u16* __restrict__ ktT)
{
    const int t = blockIdx.x, tid = threadIdx.x;
    const float* row = qkv + (size_t)t * QKV_N;
    float sq = 0.f, skv = 0.f;
    for (int i = tid; i < QL; i += 256)  { const float v = row[i];      sq  = fmaf(v, v, sq); }
    for (int i = tid; i < KVL; i += 256) { const float v = row[QL + i]; skv = fmaf(v, v, skv); }
#pragma unroll
    for (int off = 32; off >= 1; off >>= 1) {
        sq  += __shfl_down(sq, off, 64);
        skv += __shfl_down(skv, off, 64);
    }
    __shared__ float red[2][4];
    __shared__ float rs[2];
    const int wv = tid >> 6;
    if ((tid & 63) == 0) { red[0][wv] = sq; red[1][wv] = skv; }
    __syncthreads();
    if (tid == 0) {
        const float a = red[0][0] + red[0][1] + red[0][2] + red[0][3];
        const float b = red[1][0] + red[1][1] + red[1][2] + red[1][3];
        rs[0] = rsqrtf(a / (float)QL + 1e-6f);
        rs[1] = rsqrtf(b / (float)KVL + 1e-6f);
    }
    __syncthreads();
    const float rq = rs[0], rkv = rs[1];
    for (int i = tid; i < QL; i += 256)
        qanorm[(size_t)t * QL + i] = f2b(row[i] * rq * qa_w[i]);
    for (int i = tid; i < KVL; i += 256) {
        const u16 b = f2b(row[QL + i] * rkv * kva_w[i]);
        kfull[(size_t)t * KFULL + i] = b;
        ktT[(size_t)i * KTT_LD + t] = b;
    }
    if (tid < 32) {
        const float pos = (float)positions[t];
        const float inv = __expf(-(float)tid * ROPE_K);
        float s, c;
        __sincosf(pos * inv, &s, &c);
        const float x1 = row[QL + KVL + 2 * tid];
        const float x2 = row[QL + KVL + 2 * tid + 1];
        kfull[(size_t)t * KFULL + KVL + 2 * tid]     = f2b(x1 * c - x2 * s);
        kfull[(size_t)t * KFULL + KVL + 2 * tid + 1] = f2b(x2 * c + x1 * s);
    }
}

// ---------------------------------------------------------------------------
// Absorbed q_nope (f32 VALU), output bf16 pre-scaled: qf[h][t][l]
// ---------------------------------------------------------------------------
__global__ __launch_bounds__(256) void gemm_qnope_kernel(
    const float* __restrict__ q, const float* __restrict__ w_kvb,
    u16* __restrict__ qf)
{
    const int h = blockIdx.z;
    const int bn = blockIdx.x * 64;   // l
    const int bm = blockIdx.y * 64;   // t
    const int tid = threadIdx.x;
    __shared__ float As[16][68];
    __shared__ float Bs[16][68];
    const int tx = tid & 15, ty = tid >> 4;
    float acc[4][4];
#pragma unroll
    for (int i = 0; i < 4; ++i)
#pragma unroll
        for (int j = 0; j < 4; ++j) acc[i][j] = 0.f;

    const float* Abase = q + (size_t)bm * QB_N + h * (DN + DR);
    const float* Bbase = w_kvb + (size_t)bn * KVB_N + h * (DN + DV);
    const int row = tid >> 2, kq = (tid & 3) << 2;
    for (int k0 = 0; k0 < DN; k0 += 16) {
        {
            const float4 a4 = *(const float4*)(Abase + (size_t)row * QB_N + k0 + kq);
            As[kq + 0][row] = a4.x; As[kq + 1][row] = a4.y;
            As[kq + 2][row] = a4.z; As[kq + 3][row] = a4.w;
            const float4 b4 = *(const float4*)(Bbase + (size_t)row * KVB_N + k0 + kq);
            Bs[kq + 0][row] = b4.x; Bs[kq + 1][row] = b4.y;
            Bs[kq + 2][row] = b4.z; Bs[kq + 3][row] = b4.w;
        }
        __syncthreads();
#pragma unroll
        for (int kk = 0; kk < 16; ++kk) {
            float a[4], b[4];
            *(float4*)a = *(const float4*)(&As[kk][ty * 4]);
            *(float4*)b = *(const float4*)(&Bs[kk][tx * 4]);
#pragma unroll
            for (int i = 0; i < 4; ++i)
#pragma unroll
                for (int j = 0; j < 4; ++j)
                    acc[i][j] = fmaf(a[i], b[j], acc[i][j]);
        }
        __syncthreads();
    }
#pragma unroll
    for (int i = 0; i < 4; ++i)
#pragma unroll
        for (int j = 0; j < 4; ++j)
            qf[((size_t)h * T_SEQ + bm + ty * 4 + i) * KFULL + bn + tx * 4 + j] =
                f2b(acc[i][j] * SCALE_C);
}

// ---------------------------------------------------------------------------
// RoPE on q_pe -> qf[h][t][512:576] bf16, pre-scaled.
// ---------------------------------------------------------------------------
__global__ __launch_bounds__(256) void rope_qpe_kernel(
    const float* __restrict__ q, const int* __restrict__ positions,
    u16* __restrict__ qf)
{
    const int t = blockIdx.x, tid = threadIdx.x;
    const float pos = (float)positions[t];
    for (int p = tid; p < NH * 32; p += 256) {
        const int h = p >> 5, i = p & 31;
        const float inv = __expf(-(float)i * ROPE_K);
        float s, c;
        __sincosf(pos * inv, &s, &c);
        const float* src = q + (size_t)t * QB_N + h * (DN + DR) + DN;
        u16* dst = qf + ((size_t)h * T_SEQ + t) * KFULL + KVL;
        const float x1 = src[2 * i], x2 = src[2 * i + 1];
        dst[2 * i]     = f2b(SCALE_C * (x1 * c - x2 * s));
        dst[2 * i + 1] = f2b(SCALE_C * (x2 * c + x1 * s));
    }
}

// ---------------------------------------------------------------------------
// MFMA flash attention, balanced tile-pair schedule.
// Grid (16, NH) = 256 blocks = exactly 1 block/CU. Block (p,h) processes
// 64-row q-tiles p and 31-p sequentially: cost (2p+2)+(64-2p) = 68 K-tile
// iterations for EVERY block -> zero static imbalance, no drain tail, no
// cross-block LDS contention.
// 4 waves x 16 q-rows; Q (16x576) held in registers (18 v8bf / wave).
// Per iter: prefetch K+V(kt+1) global->regs (issued before compute, written
// to LDS after the post-PV barrier = T14 split, one full iter of latency
// cover); QK 36 MFMA from LDS; in-register online softmax (skip O-rescale
// when max unchanged); PV 32 MFMA from LDS. 2 barriers/iter (was 4).
// LDS strides (584 / 40) give exactly 8 lanes per start-bank class on every
// ds_read_b128 / ds_write_b128 -> conflict-optimal.
// ---------------------------------------------------------------------------
__global__ __launch_bounds__(256, 1) void attn_mfma(
    const u16* __restrict__ qf, const u16* __restrict__ kfull,
    const u16* __restrict__ ktT, u16* __restrict__ o_lat)
{
    __shared__ u16 ks_s[32 * 584];   // K tile  [32 keys][576+pad]   37,376 B
    __shared__ u16 vt_s[512 * 40];   // V^T tile [512 vdim][32+pad]  40,960 B
    __shared__ u16 pt_s[64 * 40];    // P tile  [64 qrow][32+pad]     5,120 B
    const int h = blockIdx.y;
    const int pr = blockIdx.x;                 // pair index 0..15
    const int tid = threadIdx.x, lane = tid & 63, wave = tid >> 6;
    const int g = lane >> 4, l15 = lane & 15;
    const int ksr = tid >> 3, ksc = tid & 7;   // K staging: 32 rows x 8 col-threads
    const int vsr = tid >> 2, vsc = tid & 3;   // V staging: 64 rows x 4 col-threads

    const u16* ksrc = kfull + (size_t)ksr * KFULL + ksc * 8;
    const u16* vsrc = ktT + (size_t)vsr * KTT_LD + vsc * 8;

#pragma unroll 1
    for (int hv = 0; hv < 2; ++hv) {
        const int tile = hv ? (31 - pr) : pr;
        const int qt0 = tile * 64;
        const int nk = 2 * tile + 2;

        // ---- Q tile into registers (held for the whole K loop) ----
        v8bf q[18];
        {
            const u16* qp = qf + ((size_t)h * T_SEQ + qt0 + wave * 16 + l15) * KFULL + g * 8;
#pragma unroll
            for (int c = 0; c < 18; ++c) q[c] = *(const v8bf*)(qp + c * 32);
        }
        v4f acc[32];
#pragma unroll
        for (int v = 0; v < 32; ++v) acc[v] = (v4f){0.f, 0.f, 0.f, 0.f};
        float mr[4] = {-1e30f, -1e30f, -1e30f, -1e30f};
        float lr[4] = {0.f, 0.f, 0.f, 0.f};

        uint4 kreg[9], vreg[8];
        // ---- prologue: stage K/V tile 0 ----
#pragma unroll
        for (int i = 0; i < 9; ++i) kreg[i] = *(const uint4*)(ksrc + i * 64);
#pragma unroll
        for (int i = 0; i < 8; ++i) vreg[i] = *(const uint4*)(vsrc + (size_t)i * 64 * KTT_LD);
        __syncthreads();   // previous tile's LDS readers done (no-op first pass)
#pragma unroll
        for (int i = 0; i < 9; ++i) *(uint4*)(ks_s + ksr * 584 + ksc * 8 + i * 64) = kreg[i];
#pragma unroll
        for (int i = 0; i < 8; ++i) *(uint4*)(vt_s + (vsr + i * 64) * 40 + vsc * 8) = vreg[i];
        __syncthreads();

        for (int kt = 0; kt < nk; ++kt) {
            const int kt0 = kt * 32;
            // ---- issue next-tile global loads (consumed after post-PV barrier) ----
            if (kt + 1 < nk) {
#pragma unroll
                for (int i = 0; i < 9; ++i)
                    kreg[i] = *(const uint4*)(ksrc + (size_t)(kt0 + 32) * KFULL + i * 64);
#pragma unroll
                for (int i = 0; i < 8; ++i)
                    vreg[i] = *(const uint4*)(vsrc + (size_t)i * 64 * KTT_LD + kt0 + 32);
            }
            // ---- S = Q K^T (two 16-key column tiles), K-dim 576 = 18x32 ----
            v4f s0 = (v4f){0.f, 0.f, 0.f, 0.f}, s1 = (v4f){0.f, 0.f, 0.f, 0.f};
#pragma unroll
            for (int c = 0; c < 18; ++c) {
                const int o = c * 32 + g * 8;
                const v8bf b0 = *(const v8bf*)(ks_s + l15 * 584 + o);
                const v8bf b1 = *(const v8bf*)(ks_s + (16 + l15) * 584 + o);
                s0 = __builtin_amdgcn_mfma_f32_16x16x32_bf16(q[c], b0, s0, 0, 0, 0);
                s1 = __builtin_amdgcn_mfma_f32_16x16x32_bf16(q[c], b1, s1, 0, 0, 0);
            }
            // ---- online softmax (registers + shfl within 16-lane col group) ----
            {
                const int qr = qt0 + wave * 16 + g * 4;
                const int kc0 = kt0 + l15, kc1 = kt0 + 16 + l15;
                float alpha[4];
                int resc = 0;
#pragma unroll
                for (int r = 0; r < 4; ++r) {
                    const float sv0 = (kc0 <= qr + r) ? s0[r] : -1e30f;
                    const float sv1 = (kc1 <= qr + r) ? s1[r] : -1e30f;
                    float v = fmaxf(sv0, sv1);
                    v = fmaxf(v, __shfl_xor(v, 1, 64));
                    v = fmaxf(v, __shfl_xor(v, 2, 64));
                    v = fmaxf(v, __shfl_xor(v, 4, 64));
                    v = fmaxf(v, __shfl_xor(v, 8, 64));
                    const float mx = fmaxf(mr[r], v);
                    alpha[r] = __expf(mr[r] - mx);
                    resc |= (mx != mr[r]);
                    const float p0 = __expf(sv0 - mx);
                    const float p1 = __expf(sv1 - mx);
                    pt_s[(wave * 16 + g * 4 + r) * 40 + l15]      = f2b(p0);
                    pt_s[(wave * 16 + g * 4 + r) * 40 + 16 + l15] = f2b(p1);
                    float s = p0 + p1;
                    s += __shfl_xor(s, 1, 64);
                    s += __shfl_xor(s, 2, 64);
                    s += __shfl_xor(s, 4, 64);
                    s += __shfl_xor(s, 8, 64);
                    mr[r] = mx;
                    lr[r] = lr[r] * alpha[r] + s;
                }
                if (__any(resc)) {
#pragma unroll
                    for (int v = 0; v < 32; ++v) {
                        acc[v][0] *= alpha[0]; acc[v][1] *= alpha[1];
                        acc[v][2] *= alpha[2]; acc[v][3] *= alpha[3];
                    }
                }
            }
            asm volatile("s_waitcnt lgkmcnt(0)" ::: "memory");   // P writes visible (same wave)
            __builtin_amdgcn_sched_barrier(0);
            // ---- O += P V ----
            {
                const v8bf pf = *(const v8bf*)(pt_s + (wave * 16 + l15) * 40 + g * 8);
#pragma unroll
                for (int v = 0; v < 32; ++v) {
                    const v8bf vb = *(const v8bf*)(vt_s + (v * 16 + l15) * 40 + g * 8);
                    acc[v] = __builtin_amdgcn_mfma_f32_16x16x32_bf16(pf, vb, acc[v], 0, 0, 0);
                }
            }
            __syncthreads();   // all waves done reading ks_s/vt_s
            if (kt + 1 < nk) {
#pragma unroll
                for (int i = 0; i < 9; ++i) *(uint4*)(ks_s + ksr * 584 + ksc * 8 + i * 64) = kreg[i];
#pragma unroll
                for (int i = 0; i < 8; ++i) *(uint4*)(vt_s + (vsr + i * 64) * 40 + vsc * 8) = vreg[i];
                __syncthreads();   // staged tile visible
            }
        }
        // ---- normalize + store ----
        const float li0 = 1.f / lr[0], li1 = 1.f / lr[1], li2 = 1.f / lr[2], li3 = 1.f / lr[3];
        u16* op = o_lat + ((size_t)h * T_SEQ + qt0 + wave * 16 + g * 4) * 512 + l15;
#pragma unroll
        for (int v = 0; v < 32; ++v) {
            op[0 * 512 + v * 16] = f2b(acc[v][0] * li0);
            op[1 * 512 + v * 16] = f2b(acc[v][1] * li1);
            op[2 * 512 + v * 16] = f2b(acc[v][2] * li2);
            op[3 * 512 + v * 16] = f2b(acc[v][3] * li3);
        }
    }
}

// ---------------------------------------------------------------------------
extern "C" void kernel_launch(void* const* d_in, const int* in_sizes, int n_in,
                              void* d_out, int out_size, void* d_ws, size_t ws_size,
                              hipStream_t stream)
{
    const int*   positions = (const int*)d_in[0];
    const float* hs        = (const float*)d_in[1];
    const float* w_fused   = (const float*)d_in[2];
    const float* w_qb      = (const float*)d_in[3];
    const float* w_kvb     = (const float*)d_in[4];
    const float* w_o       = (const float*)d_in[5];
    const float* qa_w      = (const float*)d_in[6];
    const float* kva_w     = (const float*)d_in[7];
    float* out = (float*)d_out;
    char*  ws  = (char*)d_ws;

    // workspace layout (bytes), with phase-disjoint aliasing:
    // R0 (38,010,880): [wfT 2176x5120 bf16][wqbT 3072x1536][qanorm 2048x1536]  -> later o_lat 16x2048x512
    // R1 (17,301,504): qkv f32 2048x2112                                       -> later o_mid 2048x2048 bf16
    // R2 (25,165,824): hs_bf 2048x5120 bf16 -> qmat f32 2048x3072 -> woT 5120x2048 bf16
    // R3: wvcT 16x128x512 bf16 | R4: kfull bf16 | R5: ktT bf16 [512][2080] | R6: qf bf16
    char* R0 = ws;
    char* R1 = R0 + 38010880;
    char* R2 = R1 + 17301504;
    char* R3 = R2 + 25165824;
    char* R4 = R3 + 2097152;
    char* R5 = R4 + 2359296;
    char* R6 = R5 + 2162688;     // ktT 512*2080*2 = 2,129,920 B; R6 end ~124.85MB

    u16*   wfT    = (u16*)R0;
    u16*   wqbT   = (u16*)(R0 + 22282240);
    u16*   qanorm = (u16*)(R0 + 31719424);
    u16*   o_lat  = (u16*)R0;
    float* qkv    = (float*)R1;
    u16*   o_mid  = (u16*)R1;
    u16*   hs_bf  = (u16*)R2;
    float* qmat   = (float*)R2;
    u16*   woT    = (u16*)R2;
    u16*   wvcT   = (u16*)R3;
    u16*   kfull  = (u16*)R4;
    u16*   ktT    = (u16*)R5;
    u16*   qf     = (u16*)R6;

    // 1. convert hs -> bf16
    cvt_bf16<<<(T_SEQ * HID / 4 + 255) / 256, 256, 0, stream>>>(hs, hs_bf, T_SEQ * HID / 4);
    // 2. transpose-convert w_fused -> wfT [2112(pad2176)][5120]
    transcvt<<<dim3(HID / 32, QKV_N / 32, 1), 256, 0, stream>>>(w_fused, wfT, QKV_N, 0, 0, 0, HID);
    // 3. qkv = hs @ w_fused   (f32 out)
    gemm_bt<<<dim3((QKV_N + 127) / 128, T_SEQ / 128), 256, 0, stream>>>(
        hs_bf, wfT, qkv, T_SEQ, QKV_N, HID);
    // 4. transpose-convert w_qb -> wqbT [3072][1536]
    transcvt<<<dim3(QL / 32, QB_N / 32, 1), 256, 0, stream>>>(w_qb, wqbT, QB_N, 0, 0, 0, QL);
    // 5. rmsnorms + k_pe rope -> qanorm bf16, kfull bf16, ktT bf16
    norm_rope_kernel<<<T_SEQ, 256, 0, stream>>>(qkv, qa_w, kva_w, positions, qanorm, kfull, ktT);
    // 6. qmat = qanorm @ w_qb  (f32 out; overwrites hs_bf region)
    gemm_bt<<<dim3(QB_N / 128, T_SEQ / 128), 256, 0, stream>>>(
        qanorm, wqbT, qmat, T_SEQ, QB_N, QL);
    // 7. absorbed q_nope + q_pe rope -> qf bf16 (pre-scaled)
    gemm_qnope_kernel<<<dim3(KVL / 64, T_SEQ / 64, NH), 256, 0, stream>>>(qmat, w_kvb, qf);
    rope_qpe_kernel<<<T_SEQ, 256, 0, stream>>>(qmat, positions, qf);
    // 8. wvcT[h][v][l] from w_kvb
    transcvt<<<dim3(KVL / 32, DV / 32, NH), 256, 0, stream>>>(
        w_kvb, wvcT, KVB_N, DN, DN + DV, (long)DV * KVL, KVL);
    // 9. balanced tile-pair MFMA flash attention -> o_lat bf16
    attn_mfma<<<dim3(16, NH), 256, 0, stream>>>(qf, kfull, ktT, o_lat);
    // 10. o_mid = per-head o_lat @ w_vc  (bf16 out; overwrites qkv)
    gemm_vc<<<dim3(T_SEQ / 128, NH), 256, 0, stream>>>(o_lat, wvcT, o_mid);
    // 11. transpose-convert w_o -> woT [5120][2048] (overwrites qmat)
    transcvt<<<dim3(OD / 32, HID / 32, 1), 256, 0, stream>>>(w_o, woT, HID, 0, 0, 0, OD);
    // 12. out = o_mid @ w_o  (f32 out)
    gemm_bt<<<dim3(HID / 128, T_SEQ / 128), 256, 0, stream>>>(
        o_mid, woT, out, T_SEQ, HID, OD);
}

// Round 4
// 1001.491 us; speedup vs baseline: 1.2198x; 1.0933x over previous
//
#include <hip/hip_runtime.h>
#include <math.h>

typedef unsigned short u16;
typedef __bf16 v8bf __attribute__((ext_vector_type(8)));
typedef float   v4f  __attribute__((ext_vector_type(4)));

#define T_SEQ 2048
#define HID   5120
#define NH    16
#define DN    128
#define DR    64
#define DV    128
#define QL    1536
#define KVL   512
#define QKV_N (QL + KVL + DR)    // 2112
#define QB_N  (NH * (DN + DR))   // 3072
#define KVB_N (NH * (DN + DV))   // 4096
#define KFULL (KVL + DR)         // 576
#define OD    (NH * DV)          // 2048
#define SCALE_C 0.07216878364870322f       // (DN+DR)^-0.5
#define ROPE_K  0.28782313662425576f       // ln(10000)/32

__device__ __forceinline__ u16 f2b(float f) {
    unsigned int u = __float_as_uint(f);
    return (u16)((u + 0x7fffu + ((u >> 16) & 1u)) >> 16);
}

// qfT element index: chunk-major 16-row tiles, fully coalesced fragment loads.
// u16 idx = (((h*128 + (t>>4))*72 + (d>>3))*16 + (t&15))*8 + (d&7)
__device__ __forceinline__ size_t qft_idx(int h, int t, int d) {
    return ((((size_t)h * 128 + (t >> 4)) * 72 + (d >> 3)) * 16 + (t & 15)) * 8 + (d & 7);
}

#if __has_builtin(__builtin_amdgcn_global_load_lds)
#define ASYNC_CP16(gp, lp) __builtin_amdgcn_global_load_lds( \
    (__attribute__((address_space(1))) void*)(gp),           \
    (__attribute__((address_space(3))) void*)(lp), 16, 0, 0)
#else
#define ASYNC_CP16(gp, lp) do { *(uint4*)(lp) = *(const uint4*)(gp); } while (0)
#endif

// ---------------------------------------------------------------------------
// f32 -> bf16 elementwise (n4 = count/4)
// ---------------------------------------------------------------------------
__global__ __launch_bounds__(256) void cvt_bf16(
    const float* __restrict__ in, u16* __restrict__ out, int n4)
{
    int i = blockIdx.x * 256 + threadIdx.x;
    if (i < n4) {
        float4 v = ((const float4*)in)[i];
        ushort4 o;
        o.x = f2b(v.x); o.y = f2b(v.y); o.z = f2b(v.z); o.w = f2b(v.w);
        ((ushort4*)out)[i] = o;
    }
}

// ---------------------------------------------------------------------------
// Transpose+convert: out[n][k] (bf16, row stride Kd) = in[k][col0+z*zcol+n] (f32)
// ---------------------------------------------------------------------------
__global__ __launch_bounds__(256) void transcvt(
    const float* __restrict__ in, u16* __restrict__ out,
    int ldin, int col0, int zcol, long out_z, int Kd)
{
    __shared__ u16 tile[32][33];
    const int bk = blockIdx.x * 32, bn = blockIdx.y * 32, z = blockIdx.z;
    const int r = threadIdx.x >> 3, cg = (threadIdx.x & 7) * 4;
    const float4 v = *(const float4*)(in + (size_t)(bk + r) * ldin + col0 + (size_t)z * zcol + bn + cg);
    tile[r][cg + 0] = f2b(v.x); tile[r][cg + 1] = f2b(v.y);
    tile[r][cg + 2] = f2b(v.z); tile[r][cg + 3] = f2b(v.w);
    __syncthreads();
    ushort4 o;
    o.x = tile[cg + 0][r]; o.y = tile[cg + 1][r];
    o.z = tile[cg + 2][r]; o.w = tile[cg + 3][r];
    *(ushort4*)(out + (size_t)z * out_z + (size_t)(bn + r) * Kd + bk + cg) = o;
}

// ---------------------------------------------------------------------------
// bf16 MFMA GEMM (m97-style): C(f32, MxN) = A(bf16 MxK) * Bt(bf16 NxK)^T
// ---------------------------------------------------------------------------
__global__ __launch_bounds__(256, 2) void gemm_bt(
    const u16* __restrict__ A, const u16* __restrict__ Bt,
    float* __restrict__ C, int M, int N, int K)
{
    __shared__ u16 As[128 * 32], Bs[128 * 32];
    const int tid = threadIdx.x, lane = tid & 63, wave = tid >> 6;
    const int g = lane >> 4, l15 = lane & 15;
    const int bm = blockIdx.y * 128, bn = blockIdx.x * 128;
    const int wm = (wave & 1) * 64, wn = (wave >> 1) * 64;
    const int srow = tid >> 2, skq = (tid & 3) * 8;
    v4f acc[4][4];
#pragma unroll
    for (int i = 0; i < 4; ++i)
#pragma unroll
        for (int j = 0; j < 4; ++j) acc[i][j] = (v4f){0.f, 0.f, 0.f, 0.f};

    for (int k0 = 0; k0 < K; k0 += 32) {
        ASYNC_CP16(A  + (size_t)(bm + srow) * K + k0 + skq,      &As[tid * 8]);
        ASYNC_CP16(A  + (size_t)(bm + 64 + srow) * K + k0 + skq, &As[2048 + tid * 8]);
        ASYNC_CP16(Bt + (size_t)(bn + srow) * K + k0 + skq,      &Bs[tid * 8]);
        ASYNC_CP16(Bt + (size_t)(bn + 64 + srow) * K + k0 + skq, &Bs[2048 + tid * 8]);
        __syncthreads();
        v8bf af[4], bq[4];
#pragma unroll
        for (int mi = 0; mi < 4; ++mi) af[mi] = *(const v8bf*)&As[(wm + mi * 16 + l15) * 32 + g * 8];
#pragma unroll
        for (int ni = 0; ni < 4; ++ni) bq[ni] = *(const v8bf*)&Bs[(wn + ni * 16 + l15) * 32 + g * 8];
#pragma unroll
        for (int mi = 0; mi < 4; ++mi)
#pragma unroll
            for (int ni = 0; ni < 4; ++ni)
                acc[mi][ni] = __builtin_amdgcn_mfma_f32_16x16x32_bf16(af[mi], bq[ni], acc[mi][ni], 0, 0, 0);
        __syncthreads();
    }
#pragma unroll
    for (int mi = 0; mi < 4; ++mi)
#pragma unroll
        for (int ni = 0; ni < 4; ++ni) {
            const int col = bn + wn + ni * 16 + l15;
            if (col < N) {
#pragma unroll
                for (int r = 0; r < 4; ++r)
                    C[(size_t)(bm + wm + mi * 16 + g * 4 + r) * N + col] = acc[mi][ni][r];
            }
        }
}

// ---------------------------------------------------------------------------
// Batched per-head w_vc GEMM: o_mid[t][h*128+v] = o_lat_h(2048x512) @ wvcT_h(128x512)^T
// ---------------------------------------------------------------------------
__global__ __launch_bounds__(256, 2) void gemm_vc(
    const u16* __restrict__ o_lat, const u16* __restrict__ wvcT,
    u16* __restrict__ o_mid)
{
    __shared__ u16 As[128 * 32], Bs[128 * 32];
    const int tid = threadIdx.x, lane = tid & 63, wave = tid >> 6;
    const int g = lane >> 4, l15 = lane & 15;
    const int h = blockIdx.y;
    const int bm = blockIdx.x * 128;
    const u16* A  = o_lat + (size_t)h * T_SEQ * 512;
    const u16* Bt = wvcT + (size_t)h * 128 * 512;
    const int wm = (wave & 1) * 64, wn = (wave >> 1) * 64;
    const int srow = tid >> 2, skq = (tid & 3) * 8;
    v4f acc[4][4];
#pragma unroll
    for (int i = 0; i < 4; ++i)
#pragma unroll
        for (int j = 0; j < 4; ++j) acc[i][j] = (v4f){0.f, 0.f, 0.f, 0.f};

    for (int k0 = 0; k0 < 512; k0 += 32) {
        ASYNC_CP16(A  + (size_t)(bm + srow) * 512 + k0 + skq,      &As[tid * 8]);
        ASYNC_CP16(A  + (size_t)(bm + 64 + srow) * 512 + k0 + skq, &As[2048 + tid * 8]);
        ASYNC_CP16(Bt + (size_t)(srow) * 512 + k0 + skq,           &Bs[tid * 8]);
        ASYNC_CP16(Bt + (size_t)(64 + srow) * 512 + k0 + skq,      &Bs[2048 + tid * 8]);
        __syncthreads();
        v8bf af[4], bq[4];
#pragma unroll
        for (int mi = 0; mi < 4; ++mi) af[mi] = *(const v8bf*)&As[(wm + mi * 16 + l15) * 32 + g * 8];
#pragma unroll
        for (int ni = 0; ni < 4; ++ni) bq[ni] = *(const v8bf*)&Bs[(wn + ni * 16 + l15) * 32 + g * 8];
#pragma unroll
        for (int mi = 0; mi < 4; ++mi)
#pragma unroll
            for (int ni = 0; ni < 4; ++ni)
                acc[mi][ni] = __builtin_amdgcn_mfma_f32_16x16x32_bf16(af[mi], bq[ni], acc[mi][ni], 0, 0, 0);
        __syncthreads();
    }
#pragma unroll
    for (int mi = 0; mi < 4; ++mi)
#pragma unroll
        for (int ni = 0; ni < 4; ++ni)
#pragma unroll
            for (int r = 0; r < 4; ++r)
                o_mid[(size_t)(bm + wm + mi * 16 + g * 4 + r) * OD + h * 128 + wn + ni * 16 + l15] =
                    f2b(acc[mi][ni][r]);
}

// ---------------------------------------------------------------------------
// Fused rmsnorms + k_pe rope. Writes qanorm bf16, kfull bf16 [T][576],
// ktT2 bf16 tile-major [64 kt][512 vdim][32 keys].
// ---------------------------------------------------------------------------
__global__ __launch_bounds__(256) void norm_rope_kernel(
    const float* __restrict__ qkv, const float* __restrict__ qa_w,
    const float* __restrict__ kva_w, const int* __restrict__ positions,
    u16* __restrict__ qanorm, u16* __restrict__ kfull, u16* __restrict__ ktT2)
{
    const int t = blockIdx.x, tid = threadIdx.x;
    const float* row = qkv + (size_t)t * QKV_N;
    float sq = 0.f, skv = 0.f;
    for (int i = tid; i < QL; i += 256)  { const float v = row[i];      sq  = fmaf(v, v, sq); }
    for (int i = tid; i < KVL; i += 256) { const float v = row[QL + i]; skv = fmaf(v, v, skv); }
#pragma unroll
    for (int off = 32; off >= 1; off >>= 1) {
        sq  += __shfl_down(sq, off, 64);
        skv += __shfl_down(skv, off, 64);
    }
    __shared__ float red[2][4];
    __shared__ float rs[2];
    const int wv = tid >> 6;
    if ((tid & 63) == 0) { red[0][wv] = sq; red[1][wv] = skv; }
    __syncthreads();
    if (tid == 0) {
        const float a = red[0][0] + red[0][1] + red[0][2] + red[0][3];
        const float b = red[1][0] + red[1][1] + red[1][2] + red[1][3];
        rs[0] = rsqrtf(a / (float)QL + 1e-6f);
        rs[1] = rsqrtf(b / (float)KVL + 1e-6f);
    }
    __syncthreads();
    const float rq = rs[0], rkv = rs[1];
    for (int i = tid; i < QL; i += 256)
        qanorm[(size_t)t * QL + i] = f2b(row[i] * rq * qa_w[i]);
    for (int i = tid; i < KVL; i += 256) {
        const u16 b = f2b(row[QL + i] * rkv * kva_w[i]);
        kfull[(size_t)t * KFULL + i] = b;
        ktT2[((size_t)(t >> 5) * 512 + i) * 32 + (t & 31)] = b;
    }
    if (tid < 32) {
        const float pos = (float)positions[t];
        const float inv = __expf(-(float)tid * ROPE_K);
        float s, c;
        __sincosf(pos * inv, &s, &c);
        const float x1 = row[QL + KVL + 2 * tid];
        const float x2 = row[QL + KVL + 2 * tid + 1];
        kfull[(size_t)t * KFULL + KVL + 2 * tid]     = f2b(x1 * c - x2 * s);
        kfull[(size_t)t * KFULL + KVL + 2 * tid + 1] = f2b(x2 * c + x1 * s);
    }
}

// ---------------------------------------------------------------------------
// Absorbed q_nope (f32 VALU), output bf16 pre-scaled into qfT chunk-major layout.
// ---------------------------------------------------------------------------
__global__ __launch_bounds__(256) void gemm_qnope_kernel(
    const float* __restrict__ q, const float* __restrict__ w_kvb,
    u16* __restrict__ qfT)
{
    const int h = blockIdx.z;
    const int bn = blockIdx.x * 64;   // l
    const int bm = blockIdx.y * 64;   // t
    const int tid = threadIdx.x;
    __shared__ float As[16][68];
    __shared__ float Bs[16][68];
    const int tx = tid & 15, ty = tid >> 4;
    float acc[4][4];
#pragma unroll
    for (int i = 0; i < 4; ++i)
#pragma unroll
        for (int j = 0; j < 4; ++j) acc[i][j] = 0.f;

    const float* Abase = q + (size_t)bm * QB_N + h * (DN + DR);
    const float* Bbase = w_kvb + (size_t)bn * KVB_N + h * (DN + DV);
    const int row = tid >> 2, kq = (tid & 3) << 2;
    for (int k0 = 0; k0 < DN; k0 += 16) {
        {
            const float4 a4 = *(const float4*)(Abase + (size_t)row * QB_N + k0 + kq);
            As[kq + 0][row] = a4.x; As[kq + 1][row] = a4.y;
            As[kq + 2][row] = a4.z; As[kq + 3][row] = a4.w;
            const float4 b4 = *(const float4*)(Bbase + (size_t)row * KVB_N + k0 + kq);
            Bs[kq + 0][row] = b4.x; Bs[kq + 1][row] = b4.y;
            Bs[kq + 2][row] = b4.z; Bs[kq + 3][row] = b4.w;
        }
        __syncthreads();
#pragma unroll
        for (int kk = 0; kk < 16; ++kk) {
            float a[4], b[4];
            *(float4*)a = *(const float4*)(&As[kk][ty * 4]);
            *(float4*)b = *(const float4*)(&Bs[kk][tx * 4]);
#pragma unroll
            for (int i = 0; i < 4; ++i)
#pragma unroll
                for (int j = 0; j < 4; ++j)
                    acc[i][j] = fmaf(a[i], b[j], acc[i][j]);
        }
        __syncthreads();
    }
#pragma unroll
    for (int i = 0; i < 4; ++i)
#pragma unroll
        for (int j = 0; j < 4; ++j)
            qfT[qft_idx(h, bm + ty * 4 + i, bn + tx * 4 + j)] = f2b(acc[i][j] * SCALE_C);
}

// ---------------------------------------------------------------------------
// RoPE on q_pe -> qfT[h][t][512:576] bf16, pre-scaled.
// ---------------------------------------------------------------------------
__global__ __launch_bounds__(256) void rope_qpe_kernel(
    const float* __restrict__ q, const int* __restrict__ positions,
    u16* __restrict__ qfT)
{
    const int t = blockIdx.x, tid = threadIdx.x;
    const float pos = (float)positions[t];
    for (int p = tid; p < NH * 32; p += 256) {
        const int h = p >> 5, i = p & 31;
        const float inv = __expf(-(float)i * ROPE_K);
        float s, c;
        __sincosf(pos * inv, &s, &c);
        const float* src = q + (size_t)t * QB_N + h * (DN + DR) + DN;
        const float x1 = src[2 * i], x2 = src[2 * i + 1];
        qfT[qft_idx(h, t, KVL + 2 * i)]     = f2b(SCALE_C * (x1 * c - x2 * s));
        qfT[qft_idx(h, t, KVL + 2 * i + 1)] = f2b(SCALE_C * (x2 * c + x1 * s));
    }
}

// ---------------------------------------------------------------------------
// MFMA flash attention. 512 blocks (32 slots x 16 heads), 4 waves x 16 q-rows,
// one 64-row q-tile per block. Cost-complementary BIJECTIVE slot->tile map:
// pair index p = blockIdx.x>>1 rotated per-head on 0..15, tile = p or 31-p.
// Co-resident block pairs (2 blocks/CU; register-capped) sum to ~66 iters.
// All global accesses fully coalesced (1024B/instr): qfT chunk-major,
// kfull rows linear (magic-div remap into padded LDS), ktT2 tile-major.
// Separate K/V LDS buffers -> 2 barriers/iter. Skip O-rescale when max
// unchanged. No cross-iteration register prefetch (avoids r2's LDS spill).
// ---------------------------------------------------------------------------
__global__ __launch_bounds__(256, 2) void attn_mfma(
    const u16* __restrict__ qfT, const u16* __restrict__ kfull,
    const u16* __restrict__ ktT2, u16* __restrict__ o_lat)
{
    __shared__ u16 ks_s[32 * 584];   // K tile  [32 keys][576+pad]  37,376 B
    __shared__ u16 vt_s[512 * 34];   // V^T tile [512 vdim][32+pad] 34,816 B
    __shared__ u16 pt_s[64 * 34];    // P tile  [64 qrow][32+pad]    4,352 B
    const int h = blockIdx.y;
    const int s = (((blockIdx.x >> 1) + 5 * h) & 15);           // bijection on 0..15
    const int tile = (blockIdx.x & 1) ? (31 - s) : s;           // pairs {s, 31-s} cover 0..31
    const int qt0 = tile * 64;
    const int nk = 2 * tile + 2;
    const int tid = threadIdx.x, lane = tid & 63, wave = tid >> 6;
    const int g = lane >> 4, l15 = lane & 15;

    // coalesced Q fragment base (per wave: one 16-row tile16)
    const u16* qp = qfT + (size_t)(h * 128 + (qt0 >> 4) + wave) * 9216 + g * 128 + l15 * 8;

    auto STAGE = [&](int kt) {
        const u16* kf_t = kfull + (size_t)kt * 32 * KFULL;      // 36,864 B linear
        const u16* vt_t = ktT2 + (size_t)kt * (512 * 32);       // 32,768 B linear
#pragma unroll
        for (int i = 0; i < 9; ++i) {
            const unsigned cid = tid + i * 256;                 // 16B chunks, 2304 total
            const unsigned kr = cid / 72u, kc = cid % 72u;
            *(uint4*)((char*)ks_s + kr * 1168 + kc * 16) = *(const uint4*)(kf_t + cid * 8);
        }
#pragma unroll
        for (int i = 0; i < 8; ++i) {
            const unsigned cid = tid + i * 256;                 // 2048 chunks, 4 per vrow
            *(uint4*)((char*)vt_s + (cid >> 2) * 68 + (cid & 3) * 16) = *(const uint4*)(vt_t + cid * 8);
        }
    };

    v4f acc[32];
#pragma unroll
    for (int v = 0; v < 32; ++v) acc[v] = (v4f){0.f, 0.f, 0.f, 0.f};
    float mr[4] = {-1e30f, -1e30f, -1e30f, -1e30f};
    float lr[4] = {0.f, 0.f, 0.f, 0.f};

    STAGE(0);
    __syncthreads();

    for (int kt = 0; kt < nk; ++kt) {
        const int kt0 = kt * 32;
        // ---- S = Q K^T (two 16-key column tiles), K-dim 576 = 18x32 ----
        v4f s0 = (v4f){0.f, 0.f, 0.f, 0.f}, s1 = (v4f){0.f, 0.f, 0.f, 0.f};
#pragma unroll
        for (int half = 0; half < 2; ++half) {
            v8bf aq[9];
#pragma unroll
            for (int c = 0; c < 9; ++c)
                aq[c] = *(const v8bf*)(qp + (half * 9 + c) * 512);
#pragma unroll
            for (int c = 0; c < 9; ++c) {
                const int o = (half * 9 + c) * 32 + g * 8;
                const v8bf b0 = *(const v8bf*)(ks_s + l15 * 584 + o);
                const v8bf b1 = *(const v8bf*)(ks_s + (16 + l15) * 584 + o);
                s0 = __builtin_amdgcn_mfma_f32_16x16x32_bf16(aq[c], b0, s0, 0, 0, 0);
                s1 = __builtin_amdgcn_mfma_f32_16x16x32_bf16(aq[c], b1, s1, 0, 0, 0);
            }
        }
        // ---- online softmax (registers + shfl within 16-lane col group) ----
        {
            const int qr = qt0 + wave * 16 + g * 4;
            const int kc0 = kt0 + l15, kc1 = kt0 + 16 + l15;
            float alpha[4];
            int resc = 0;
#pragma unroll
            for (int r = 0; r < 4; ++r) {
                const float sv0 = (kc0 <= qr + r) ? s0[r] : -1e30f;
                const float sv1 = (kc1 <= qr + r) ? s1[r] : -1e30f;
                float v = fmaxf(sv0, sv1);
                v = fmaxf(v, __shfl_xor(v, 1, 64));
                v = fmaxf(v, __shfl_xor(v, 2, 64));
                v = fmaxf(v, __shfl_xor(v, 4, 64));
                v = fmaxf(v, __shfl_xor(v, 8, 64));
                const float mx = fmaxf(mr[r], v);
                alpha[r] = __expf(mr[r] - mx);
                resc |= (mx != mr[r]);
                const float p0 = __expf(sv0 - mx);
                const float p1 = __expf(sv1 - mx);
                pt_s[(wave * 16 + g * 4 + r) * 34 + l15]      = f2b(p0);
                pt_s[(wave * 16 + g * 4 + r) * 34 + 16 + l15] = f2b(p1);
                float ss = p0 + p1;
                ss += __shfl_xor(ss, 1, 64);
                ss += __shfl_xor(ss, 2, 64);
                ss += __shfl_xor(ss, 4, 64);
                ss += __shfl_xor(ss, 8, 64);
                mr[r] = mx;
                lr[r] = lr[r] * alpha[r] + ss;
            }
            if (__any(resc)) {
#pragma unroll
                for (int v = 0; v < 32; ++v) {
                    acc[v][0] *= alpha[0]; acc[v][1] *= alpha[1];
                    acc[v][2] *= alpha[2]; acc[v][3] *= alpha[3];
                }
            }
        }
        asm volatile("s_waitcnt lgkmcnt(0)" ::: "memory");   // own P writes visible
        __builtin_amdgcn_sched_barrier(0);
        // ---- O += P V ----
        {
            const v8bf pf = *(const v8bf*)(pt_s + (wave * 16 + l15) * 34 + g * 8);
#pragma unroll
            for (int v = 0; v < 32; ++v) {
                const v8bf vb = *(const v8bf*)(vt_s + (v * 16 + l15) * 34 + g * 8);
                acc[v] = __builtin_amdgcn_mfma_f32_16x16x32_bf16(pf, vb, acc[v], 0, 0, 0);
            }
        }
        __syncthreads();   // all waves done reading ks_s/vt_s
        if (kt + 1 < nk) {
            STAGE(kt + 1);
            __syncthreads();
        }
    }
    // ---- normalize + store ----
    const float li0 = 1.f / lr[0], li1 = 1.f / lr[1], li2 = 1.f / lr[2], li3 = 1.f / lr[3];
    u16* op = o_lat + ((size_t)h * T_SEQ + qt0 + wave * 16 + g * 4) * 512 + l15;
#pragma unroll
    for (int v = 0; v < 32; ++v) {
        op[0 * 512 + v * 16] = f2b(acc[v][0] * li0);
        op[1 * 512 + v * 16] = f2b(acc[v][1] * li1);
        op[2 * 512 + v * 16] = f2b(acc[v][2] * li2);
        op[3 * 512 + v * 16] = f2b(acc[v][3] * li3);
    }
}

// ---------------------------------------------------------------------------
extern "C" void kernel_launch(void* const* d_in, const int* in_sizes, int n_in,
                              void* d_out, int out_size, void* d_ws, size_t ws_size,
                              hipStream_t stream)
{
    const int*   positions = (const int*)d_in[0];
    const float* hs        = (const float*)d_in[1];
    const float* w_fused   = (const float*)d_in[2];
    const float* w_qb      = (const float*)d_in[3];
    const float* w_kvb     = (const float*)d_in[4];
    const float* w_o       = (const float*)d_in[5];
    const float* qa_w      = (const float*)d_in[6];
    const float* kva_w     = (const float*)d_in[7];
    float* out = (float*)d_out;
    char*  ws  = (char*)d_ws;

    // workspace layout (bytes), with phase-disjoint aliasing:
    // R0 (38,010,880): [wfT 2176x5120 bf16][wqbT 3072x1536][qanorm 2048x1536]  -> later o_lat 16x2048x512
    // R1 (17,301,504): qkv f32 2048x2112                                       -> later o_mid 2048x2048 bf16
    // R2 (25,165,824): hs_bf 2048x5120 bf16 -> qmat f32 2048x3072 -> woT 5120x2048 bf16
    // R3: wvcT 16x128x512 bf16 | R4: kfull bf16 | R5: ktT2 bf16 [64][512][32] | R6: qfT bf16
    char* R0 = ws;
    char* R1 = R0 + 38010880;
    char* R2 = R1 + 17301504;
    char* R3 = R2 + 25165824;
    char* R4 = R3 + 2097152;
    char* R5 = R4 + 2359296;
    char* R6 = R5 + 2162688;     // ktT2 = 64*512*32*2 = 2,097,152 B

    u16*   wfT    = (u16*)R0;
    u16*   wqbT   = (u16*)(R0 + 22282240);
    u16*   qanorm = (u16*)(R0 + 31719424);
    u16*   o_lat  = (u16*)R0;
    float* qkv    = (float*)R1;
    u16*   o_mid  = (u16*)R1;
    u16*   hs_bf  = (u16*)R2;
    float* qmat   = (float*)R2;
    u16*   woT    = (u16*)R2;
    u16*   wvcT   = (u16*)R3;
    u16*   kfull  = (u16*)R4;
    u16*   ktT2   = (u16*)R5;
    u16*   qfT    = (u16*)R6;

    // 1. convert hs -> bf16
    cvt_bf16<<<(T_SEQ * HID / 4 + 255) / 256, 256, 0, stream>>>(hs, hs_bf, T_SEQ * HID / 4);
    // 2. transpose-convert w_fused -> wfT [2112(pad2176)][5120]
    transcvt<<<dim3(HID / 32, QKV_N / 32, 1), 256, 0, stream>>>(w_fused, wfT, QKV_N, 0, 0, 0, HID);
    // 3. qkv = hs @ w_fused   (f32 out)
    gemm_bt<<<dim3((QKV_N + 127) / 128, T_SEQ / 128), 256, 0, stream>>>(
        hs_bf, wfT, qkv, T_SEQ, QKV_N, HID);
    // 4. transpose-convert w_qb -> wqbT [3072][1536]
    transcvt<<<dim3(QL / 32, QB_N / 32, 1), 256, 0, stream>>>(w_qb, wqbT, QB_N, 0, 0, 0, QL);
    // 5. rmsnorms + k_pe rope -> qanorm bf16, kfull bf16, ktT2 bf16
    norm_rope_kernel<<<T_SEQ, 256, 0, stream>>>(qkv, qa_w, kva_w, positions, qanorm, kfull, ktT2);
    // 6. qmat = qanorm @ w_qb  (f32 out; overwrites hs_bf region)
    gemm_bt<<<dim3(QB_N / 128, T_SEQ / 128), 256, 0, stream>>>(
        qanorm, wqbT, qmat, T_SEQ, QB_N, QL);
    // 7. absorbed q_nope + q_pe rope -> qfT bf16 (pre-scaled, chunk-major)
    gemm_qnope_kernel<<<dim3(KVL / 64, T_SEQ / 64, NH), 256, 0, stream>>>(qmat, w_kvb, qfT);
    rope_qpe_kernel<<<T_SEQ, 256, 0, stream>>>(qmat, positions, qfT);
    // 8. wvcT[h][v][l] from w_kvb
    transcvt<<<dim3(KVL / 32, DV / 32, NH), 256, 0, stream>>>(
        w_kvb, wvcT, KVB_N, DN, DN + DV, (long)DV * KVL, KVL);
    // 9. MFMA flash attention -> o_lat bf16 (overwrites wfT/wqbT/qanorm)
    attn_mfma<<<dim3(32, NH), 256, 0, stream>>>(qfT, kfull, ktT2, o_lat);
    // 10. o_mid = per-head o_lat @ w_vc  (bf16 out; overwrites qkv)
    gemm_vc<<<dim3(T_SEQ / 128, NH), 256, 0, stream>>>(o_lat, wvcT, o_mid);
    // 11. transpose-convert w_o -> woT [5120][2048] (overwrites qmat)
    transcvt<<<dim3(OD / 32, HID / 32, 1), 256, 0, stream>>>(w_o, woT, HID, 0, 0, 0, OD);
    // 12. out = o_mid @ w_o  (f32 out)
    gemm_bt<<<dim3(HID / 128, T_SEQ / 128), 256, 0, stream>>>(
        o_mid, woT, out, T_SEQ, HID, OD);
}

// Round 5
// 781.917 us; speedup vs baseline: 1.5624x; 1.2808x over previous
//
#include <hip/hip_runtime.h>
#include <math.h>

typedef unsigned short u16;
typedef __bf16 v8bf __attribute__((ext_vector_type(8)));
typedef float   v4f  __attribute__((ext_vector_type(4)));

#define T_SEQ 2048
#define HID   5120
#define NH    16
#define DN    128
#define DR    64
#define DV    128
#define QL    1536
#define KVL   512
#define QKV_N (QL + KVL + DR)    // 2112
#define QB_N  (NH * (DN + DR))   // 3072
#define KVB_N (NH * (DN + DV))   // 4096
#define KFULL (KVL + DR)         // 576
#define OD    (NH * DV)          // 2048
#define SCALE_C 0.07216878364870322f       // (DN+DR)^-0.5
#define ROPE_K  0.28782313662425576f       // ln(10000)/32

// K LDS image: [32 keys][584 u16] (576 valid + 8 pad)  = 37,376 B = 2336 x 16B
// V LDS image: [512 vdim][34 u16] (32 keys + 2 pad)    = 34,816 B = 2176 x 16B
#define KIMG_U16 18688
#define VIMG_U16 17408

__device__ __forceinline__ u16 f2b(float f) {
    unsigned int u = __float_as_uint(f);
    return (u16)((u + 0x7fffu + ((u >> 16) & 1u)) >> 16);
}

// qfT element index: chunk-major 16-row tiles, fully coalesced fragment loads.
__device__ __forceinline__ size_t qft_idx(int h, int t, int d) {
    return ((((size_t)h * 128 + (t >> 4)) * 72 + (d >> 3)) * 16 + (t & 15)) * 8 + (d & 7);
}

// DPP rotation within each 16-lane row: row_ror:n = 0x120+n
#define ROR_F(x, CTRL) __uint_as_float(__builtin_amdgcn_update_dpp( \
    0, (int)__float_as_uint(x), CTRL, 0xf, 0xf, true))

#if __has_builtin(__builtin_amdgcn_global_load_lds)
#define ASYNC_CP16(gp, lp) __builtin_amdgcn_global_load_lds( \
    (__attribute__((address_space(1))) void*)(gp),           \
    (__attribute__((address_space(3))) void*)(lp), 16, 0, 0)
#else
#define ASYNC_CP16(gp, lp) do { *(uint4*)(lp) = *(const uint4*)(gp); } while (0)
#endif

// ---------------------------------------------------------------------------
// f32 -> bf16 elementwise (n4 = count/4)
// ---------------------------------------------------------------------------
__global__ __launch_bounds__(256) void cvt_bf16(
    const float* __restrict__ in, u16* __restrict__ out, int n4)
{
    int i = blockIdx.x * 256 + threadIdx.x;
    if (i < n4) {
        float4 v = ((const float4*)in)[i];
        ushort4 o;
        o.x = f2b(v.x); o.y = f2b(v.y); o.z = f2b(v.z); o.w = f2b(v.w);
        ((ushort4*)out)[i] = o;
    }
}

// ---------------------------------------------------------------------------
// Transpose+convert: out[n][k] (bf16, row stride Kd) = in[k][col0+z*zcol+n] (f32)
// ---------------------------------------------------------------------------
__global__ __launch_bounds__(256) void transcvt(
    const float* __restrict__ in, u16* __restrict__ out,
    int ldin, int col0, int zcol, long out_z, int Kd)
{
    __shared__ u16 tile[32][33];
    const int bk = blockIdx.x * 32, bn = blockIdx.y * 32, z = blockIdx.z;
    const int r = threadIdx.x >> 3, cg = (threadIdx.x & 7) * 4;
    const float4 v = *(const float4*)(in + (size_t)(bk + r) * ldin + col0 + (size_t)z * zcol + bn + cg);
    tile[r][cg + 0] = f2b(v.x); tile[r][cg + 1] = f2b(v.y);
    tile[r][cg + 2] = f2b(v.z); tile[r][cg + 3] = f2b(v.w);
    __syncthreads();
    ushort4 o;
    o.x = tile[cg + 0][r]; o.y = tile[cg + 1][r];
    o.z = tile[cg + 2][r]; o.w = tile[cg + 3][r];
    *(ushort4*)(out + (size_t)z * out_z + (size_t)(bn + r) * Kd + bk + cg) = o;
}

// ---------------------------------------------------------------------------
// bf16 MFMA GEMM (m97-style): C(f32, MxN) = A(bf16 MxK) * Bt(bf16 NxK)^T
// ---------------------------------------------------------------------------
__global__ __launch_bounds__(256, 2) void gemm_bt(
    const u16* __restrict__ A, const u16* __restrict__ Bt,
    float* __restrict__ C, int M, int N, int K)
{
    __shared__ u16 As[128 * 32], Bs[128 * 32];
    const int tid = threadIdx.x, lane = tid & 63, wave = tid >> 6;
    const int g = lane >> 4, l15 = lane & 15;
    const int bm = blockIdx.y * 128, bn = blockIdx.x * 128;
    const int wm = (wave & 1) * 64, wn = (wave >> 1) * 64;
    const int srow = tid >> 2, skq = (tid & 3) * 8;
    v4f acc[4][4];
#pragma unroll
    for (int i = 0; i < 4; ++i)
#pragma unroll
        for (int j = 0; j < 4; ++j) acc[i][j] = (v4f){0.f, 0.f, 0.f, 0.f};

    for (int k0 = 0; k0 < K; k0 += 32) {
        ASYNC_CP16(A  + (size_t)(bm + srow) * K + k0 + skq,      &As[tid * 8]);
        ASYNC_CP16(A  + (size_t)(bm + 64 + srow) * K + k0 + skq, &As[2048 + tid * 8]);
        ASYNC_CP16(Bt + (size_t)(bn + srow) * K + k0 + skq,      &Bs[tid * 8]);
        ASYNC_CP16(Bt + (size_t)(bn + 64 + srow) * K + k0 + skq, &Bs[2048 + tid * 8]);
        __syncthreads();
        v8bf af[4], bq[4];
#pragma unroll
        for (int mi = 0; mi < 4; ++mi) af[mi] = *(const v8bf*)&As[(wm + mi * 16 + l15) * 32 + g * 8];
#pragma unroll
        for (int ni = 0; ni < 4; ++ni) bq[ni] = *(const v8bf*)&Bs[(wn + ni * 16 + l15) * 32 + g * 8];
#pragma unroll
        for (int mi = 0; mi < 4; ++mi)
#pragma unroll
            for (int ni = 0; ni < 4; ++ni)
                acc[mi][ni] = __builtin_amdgcn_mfma_f32_16x16x32_bf16(af[mi], bq[ni], acc[mi][ni], 0, 0, 0);
        __syncthreads();
    }
#pragma unroll
    for (int mi = 0; mi < 4; ++mi)
#pragma unroll
        for (int ni = 0; ni < 4; ++ni) {
            const int col = bn + wn + ni * 16 + l15;
            if (col < N) {
#pragma unroll
                for (int r = 0; r < 4; ++r)
                    C[(size_t)(bm + wm + mi * 16 + g * 4 + r) * N + col] = acc[mi][ni][r];
            }
        }
}

// ---------------------------------------------------------------------------
// Batched per-head w_vc GEMM: o_mid[t][h*128+v] = o_lat_h(2048x512) @ wvcT_h(128x512)^T
// ---------------------------------------------------------------------------
__global__ __launch_bounds__(256, 2) void gemm_vc(
    const u16* __restrict__ o_lat, const u16* __restrict__ wvcT,
    u16* __restrict__ o_mid)
{
    __shared__ u16 As[128 * 32], Bs[128 * 32];
    const int tid = threadIdx.x, lane = tid & 63, wave = tid >> 6;
    const int g = lane >> 4, l15 = lane & 15;
    const int h = blockIdx.y;
    const int bm = blockIdx.x * 128;
    const u16* A  = o_lat + (size_t)h * T_SEQ * 512;
    const u16* Bt = wvcT + (size_t)h * 128 * 512;
    const int wm = (wave & 1) * 64, wn = (wave >> 1) * 64;
    const int srow = tid >> 2, skq = (tid & 3) * 8;
    v4f acc[4][4];
#pragma unroll
    for (int i = 0; i < 4; ++i)
#pragma unroll
        for (int j = 0; j < 4; ++j) acc[i][j] = (v4f){0.f, 0.f, 0.f, 0.f};

    for (int k0 = 0; k0 < 512; k0 += 32) {
        ASYNC_CP16(A  + (size_t)(bm + srow) * 512 + k0 + skq,      &As[tid * 8]);
        ASYNC_CP16(A  + (size_t)(bm + 64 + srow) * 512 + k0 + skq, &As[2048 + tid * 8]);
        ASYNC_CP16(Bt + (size_t)(srow) * 512 + k0 + skq,           &Bs[tid * 8]);
        ASYNC_CP16(Bt + (size_t)(64 + srow) * 512 + k0 + skq,      &Bs[2048 + tid * 8]);
        __syncthreads();
        v8bf af[4], bq[4];
#pragma unroll
        for (int mi = 0; mi < 4; ++mi) af[mi] = *(const v8bf*)&As[(wm + mi * 16 + l15) * 32 + g * 8];
#pragma unroll
        for (int ni = 0; ni < 4; ++ni) bq[ni] = *(const v8bf*)&Bs[(wn + ni * 16 + l15) * 32 + g * 8];
#pragma unroll
        for (int mi = 0; mi < 4; ++mi)
#pragma unroll
            for (int ni = 0; ni < 4; ++ni)
                acc[mi][ni] = __builtin_amdgcn_mfma_f32_16x16x32_bf16(af[mi], bq[ni], acc[mi][ni], 0, 0, 0);
        __syncthreads();
    }
#pragma unroll
    for (int mi = 0; mi < 4; ++mi)
#pragma unroll
        for (int ni = 0; ni < 4; ++ni)
#pragma unroll
            for (int r = 0; r < 4; ++r)
                o_mid[(size_t)(bm + wm + mi * 16 + g * 4 + r) * OD + h * 128 + wn + ni * 16 + l15] =
                    f2b(acc[mi][ni][r]);
}

// ---------------------------------------------------------------------------
// Fused rmsnorms + k_pe rope. Writes qanorm bf16 and the K/V LDS images:
// k_img[kt][r=key&31][584] (576 valid), v_img[kt][l=vdim][34] (32 valid).
// ---------------------------------------------------------------------------
__global__ __launch_bounds__(256) void norm_rope_kernel(
    const float* __restrict__ qkv, const float* __restrict__ qa_w,
    const float* __restrict__ kva_w, const int* __restrict__ positions,
    u16* __restrict__ qanorm, u16* __restrict__ k_img, u16* __restrict__ v_img)
{
    const int t = blockIdx.x, tid = threadIdx.x;
    const float* row = qkv + (size_t)t * QKV_N;
    float sq = 0.f, skv = 0.f;
    for (int i = tid; i < QL; i += 256)  { const float v = row[i];      sq  = fmaf(v, v, sq); }
    for (int i = tid; i < KVL; i += 256) { const float v = row[QL + i]; skv = fmaf(v, v, skv); }
#pragma unroll
    for (int off = 32; off >= 1; off >>= 1) {
        sq  += __shfl_down(sq, off, 64);
        skv += __shfl_down(skv, off, 64);
    }
    __shared__ float red[2][4];
    __shared__ float rs[2];
    const int wv = tid >> 6;
    if ((tid & 63) == 0) { red[0][wv] = sq; red[1][wv] = skv; }
    __syncthreads();
    if (tid == 0) {
        const float a = red[0][0] + red[0][1] + red[0][2] + red[0][3];
        const float b = red[1][0] + red[1][1] + red[1][2] + red[1][3];
        rs[0] = rsqrtf(a / (float)QL + 1e-6f);
        rs[1] = rsqrtf(b / (float)KVL + 1e-6f);
    }
    __syncthreads();
    const float rq = rs[0], rkv = rs[1];
    for (int i = tid; i < QL; i += 256)
        qanorm[(size_t)t * QL + i] = f2b(row[i] * rq * qa_w[i]);
    const int kt = t >> 5, r = t & 31;
    u16* krow = k_img + (size_t)kt * KIMG_U16 + (size_t)r * 584;
    u16* vcol = v_img + (size_t)kt * VIMG_U16 + r;
    for (int i = tid; i < KVL; i += 256) {
        const u16 b = f2b(row[QL + i] * rkv * kva_w[i]);
        krow[i] = b;
        vcol[(size_t)i * 34] = b;
    }
    if (tid < 32) {
        const float pos = (float)positions[t];
        const float inv = __expf(-(float)tid * ROPE_K);
        float s, c;
        __sincosf(pos * inv, &s, &c);
        const float x1 = row[QL + KVL + 2 * tid];
        const float x2 = row[QL + KVL + 2 * tid + 1];
        krow[KVL + 2 * tid]     = f2b(x1 * c - x2 * s);
        krow[KVL + 2 * tid + 1] = f2b(x2 * c + x1 * s);
    }
}

// ---------------------------------------------------------------------------
// Cast qmat q_nope slices -> qn_bf[h][t][128] bf16 (row-linear per head)
// ---------------------------------------------------------------------------
__global__ __launch_bounds__(256) void cast_qnope(
    const float* __restrict__ qmat, u16* __restrict__ qn_bf)
{
    const int t = blockIdx.x, tid = threadIdx.x;
#pragma unroll
    for (int i = 0; i < 2; ++i) {
        const int p4 = (tid + i * 256) * 4;          // 0..2044
        const int h = p4 >> 7, d = p4 & 127;
        const float4 v = *(const float4*)(qmat + (size_t)t * QB_N + h * (DN + DR) + d);
        ushort4 o;
        o.x = f2b(v.x); o.y = f2b(v.y); o.z = f2b(v.z); o.w = f2b(v.w);
        *(ushort4*)(qn_bf + ((size_t)h * T_SEQ + t) * DN + d) = o;
    }
}

// ---------------------------------------------------------------------------
// Cast w_kvb kc slices -> wkc_bf[h][l][128] bf16
// ---------------------------------------------------------------------------
__global__ __launch_bounds__(256) void cast_wkc(
    const float* __restrict__ w_kvb, u16* __restrict__ wkc_bf)
{
    const int gid = blockIdx.x * 256 + threadIdx.x;  // 262,144 float4 groups
    const int p4 = gid * 4;
    const int h = p4 >> 16, rem = p4 & 65535, l = rem >> 7, d = rem & 127;
    const float4 v = *(const float4*)(w_kvb + (size_t)l * KVB_N + h * (DN + DV) + d);
    ushort4 o;
    o.x = f2b(v.x); o.y = f2b(v.y); o.z = f2b(v.z); o.w = f2b(v.w);
    *(ushort4*)(wkc_bf + (size_t)p4) = o;
}

// ---------------------------------------------------------------------------
// Absorbed q_nope via bf16 MFMA per head: qfT[h][t][l<512] = scale * qn_h @ wkc_h^T
// grid (512/128, 2048/128, NH). K = 128 (4 k-steps).
// ---------------------------------------------------------------------------
__global__ __launch_bounds__(256, 2) void gemm_qabs(
    const u16* __restrict__ qn_bf, const u16* __restrict__ wkc_bf,
    u16* __restrict__ qfT)
{
    __shared__ u16 As[128 * 32], Bs[128 * 32];
    const int tid = threadIdx.x, lane = tid & 63, wave = tid >> 6;
    const int g = lane >> 4, l15 = lane & 15;
    const int h = blockIdx.z;
    const int bm = blockIdx.y * 128, bn = blockIdx.x * 128;
    const u16* A  = qn_bf + (size_t)h * T_SEQ * DN;
    const u16* Bt = wkc_bf + (size_t)h * KVL * DN;
    const int wm = (wave & 1) * 64, wn = (wave >> 1) * 64;
    const int srow = tid >> 2, skq = (tid & 3) * 8;
    v4f acc[4][4];
#pragma unroll
    for (int i = 0; i < 4; ++i)
#pragma unroll
        for (int j = 0; j < 4; ++j) acc[i][j] = (v4f){0.f, 0.f, 0.f, 0.f};

    for (int k0 = 0; k0 < DN; k0 += 32) {
        ASYNC_CP16(A  + (size_t)(bm + srow) * DN + k0 + skq,      &As[tid * 8]);
        ASYNC_CP16(A  + (size_t)(bm + 64 + srow) * DN + k0 + skq, &As[2048 + tid * 8]);
        ASYNC_CP16(Bt + (size_t)(bn + srow) * DN + k0 + skq,      &Bs[tid * 8]);
        ASYNC_CP16(Bt + (size_t)(bn + 64 + srow) * DN + k0 + skq, &Bs[2048 + tid * 8]);
        __syncthreads();
        v8bf af[4], bq[4];
#pragma unroll
        for (int mi = 0; mi < 4; ++mi) af[mi] = *(const v8bf*)&As[(wm + mi * 16 + l15) * 32 + g * 8];
#pragma unroll
        for (int ni = 0; ni < 4; ++ni) bq[ni] = *(const v8bf*)&Bs[(wn + ni * 16 + l15) * 32 + g * 8];
#pragma unroll
        for (int mi = 0; mi < 4; ++mi)
#pragma unroll
            for (int ni = 0; ni < 4; ++ni)
                acc[mi][ni] = __builtin_amdgcn_mfma_f32_16x16x32_bf16(af[mi], bq[ni], acc[mi][ni], 0, 0, 0);
        __syncthreads();
    }
#pragma unroll
    for (int mi = 0; mi < 4; ++mi)
#pragma unroll
        for (int ni = 0; ni < 4; ++ni)
#pragma unroll
            for (int r = 0; r < 4; ++r) {
                const int t = bm + wm + mi * 16 + g * 4 + r;
                const int d = bn + wn + ni * 16 + l15;
                qfT[qft_idx(h, t, d)] = f2b(acc[mi][ni][r] * SCALE_C);
            }
}

// ---------------------------------------------------------------------------
// RoPE on q_pe -> qfT[h][t][512:576] bf16, pre-scaled.
// ---------------------------------------------------------------------------
__global__ __launch_bounds__(256) void rope_qpe_kernel(
    const float* __restrict__ q, const int* __restrict__ positions,
    u16* __restrict__ qfT)
{
    const int t = blockIdx.x, tid = threadIdx.x;
    const float pos = (float)positions[t];
    for (int p = tid; p < NH * 32; p += 256) {
        const int h = p >> 5, i = p & 31;
        const float inv = __expf(-(float)i * ROPE_K);
        float s, c;
        __sincosf(pos * inv, &s, &c);
        const float* src = q + (size_t)t * QB_N + h * (DN + DR) + DN;
        const float x1 = src[2 * i], x2 = src[2 * i + 1];
        qfT[qft_idx(h, t, KVL + 2 * i)]     = f2b(SCALE_C * (x1 * c - x2 * s));
        qfT[qft_idx(h, t, KVL + 2 * i + 1)] = f2b(SCALE_C * (x2 * c + x1 * s));
    }
}

// ---------------------------------------------------------------------------
// MFMA flash attention v3. 512 blocks (bijective balanced map), 4 waves.
// QK+softmax: wave owns q-rows 16w..16w+16 (Q loads coalesced from qfT).
// Softmax reduce via DPP row_ror (VALU, no DS-pipe shfl). P/alpha/flags -> LDS.
// PV: v-split — wave owns v-cols 128w..128w+128 for ALL 64 q-rows:
//   8 hoisted V-frag reads + 4 P + 4 alpha + 1 flag per iter (vs 33).
// Staging via global_load_lds from k_img/v_img (linear LDS images, no ds_write,
// no VGPR round-trip). K-DMA for kt+1 issues after barrier A, hides under PV.
// ---------------------------------------------------------------------------
__global__ __launch_bounds__(256, 2) void attn_mfma(
    const u16* __restrict__ qfT, const u16* __restrict__ k_img,
    const u16* __restrict__ v_img, u16* __restrict__ o_lat)
{
    __shared__ u16 ks_s[32 * 584];               // 37,376 B
    __shared__ u16 vt_s[512 * 34];               // 34,816 B
    __shared__ u16 pt_s[64 * 34];                //  4,352 B
    __shared__ __align__(16) float alpha_s[64];
    __shared__ __align__(16) float lr_s[64];
    __shared__ __align__(16) unsigned flags_s[4];
    const int h = blockIdx.y;
    const int s = (((blockIdx.x >> 1) + 5 * h) & 15);
    const int tile = (blockIdx.x & 1) ? (31 - s) : s;
    const int qt0 = tile * 64;
    const int nk = 2 * tile + 2;
    const int tid = threadIdx.x, lane = tid & 63, wave = tid >> 6;
    const int g = lane >> 4, l15 = lane & 15;

    const u16* qp = qfT + (size_t)(h * 128 + (qt0 >> 4) + wave) * 9216 + g * 128 + l15 * 8;

    auto STAGE_K = [&](int kt) {
        const char* src = (const char*)(k_img + (size_t)kt * KIMG_U16);
        char* dst = (char*)ks_s;
#pragma unroll
        for (int i = 0; i < 9; ++i)
            ASYNC_CP16(src + (tid + i * 256) * 16, dst + (tid + i * 256) * 16);
        if (tid < 32)
            ASYNC_CP16(src + (2304 + tid) * 16, dst + (2304 + tid) * 16);
    };
    auto STAGE_V = [&](int kt) {
        const char* src = (const char*)(v_img + (size_t)kt * VIMG_U16);
        char* dst = (char*)vt_s;
#pragma unroll
        for (int i = 0; i < 8; ++i)
            ASYNC_CP16(src + (tid + i * 256) * 16, dst + (tid + i * 256) * 16);
        if (tid < 128)
            ASYNC_CP16(src + (2048 + tid) * 16, dst + (2048 + tid) * 16);
    };

    v4f acc[4][8];
#pragma unroll
    for (int m = 0; m < 4; ++m)
#pragma unroll
        for (int n = 0; n < 8; ++n) acc[m][n] = (v4f){0.f, 0.f, 0.f, 0.f};
    float mr[4] = {-1e30f, -1e30f, -1e30f, -1e30f};
    float lrr[4] = {0.f, 0.f, 0.f, 0.f};

    STAGE_K(0);
    STAGE_V(0);
    asm volatile("s_waitcnt vmcnt(0)" ::: "memory");
    __syncthreads();

    for (int kt = 0; kt < nk; ++kt) {
        const int kt0 = kt * 32;
        // ---- S = Q K^T (wave's 16 q-rows x 32 keys), K-dim 576 = 18x32 ----
        v4f s0 = (v4f){0.f, 0.f, 0.f, 0.f}, s1 = (v4f){0.f, 0.f, 0.f, 0.f};
#pragma unroll
        for (int half = 0; half < 2; ++half) {
            v8bf aq[9];
#pragma unroll
            for (int c = 0; c < 9; ++c)
                aq[c] = *(const v8bf*)(qp + (half * 9 + c) * 512);
#pragma unroll
            for (int c = 0; c < 9; ++c) {
                const int o = (half * 9 + c) * 32 + g * 8;
                const v8bf b0 = *(const v8bf*)(ks_s + l15 * 584 + o);
                const v8bf b1 = *(const v8bf*)(ks_s + (16 + l15) * 584 + o);
                s0 = __builtin_amdgcn_mfma_f32_16x16x32_bf16(aq[c], b0, s0, 0, 0, 0);
                s1 = __builtin_amdgcn_mfma_f32_16x16x32_bf16(aq[c], b1, s1, 0, 0, 0);
            }
        }
        // ---- online softmax: DPP rotation reduce within 16-lane groups ----
        {
            const int qr = qt0 + wave * 16 + g * 4;
            const int kc0 = kt0 + l15, kc1 = kt0 + 16 + l15;
            float al[4];
            unsigned resc = 0;
#pragma unroll
            for (int r = 0; r < 4; ++r) {
                const float sv0 = (kc0 <= qr + r) ? s0[r] : -1e30f;
                const float sv1 = (kc1 <= qr + r) ? s1[r] : -1e30f;
                float v = fmaxf(sv0, sv1);
                v = fmaxf(v, ROR_F(v, 0x128));
                v = fmaxf(v, ROR_F(v, 0x124));
                v = fmaxf(v, ROR_F(v, 0x122));
                v = fmaxf(v, ROR_F(v, 0x121));
                const float mx = fmaxf(mr[r], v);
                al[r] = __expf(mr[r] - mx);
                resc |= (mx != mr[r]) ? 1u : 0u;
                const float p0 = __expf(sv0 - mx);
                const float p1 = __expf(sv1 - mx);
                pt_s[(wave * 16 + g * 4 + r) * 34 + l15]      = f2b(p0);
                pt_s[(wave * 16 + g * 4 + r) * 34 + 16 + l15] = f2b(p1);
                float ss = p0 + p1;
                ss += ROR_F(ss, 0x128);
                ss += ROR_F(ss, 0x124);
                ss += ROR_F(ss, 0x122);
                ss += ROR_F(ss, 0x121);
                mr[r] = mx;
                lrr[r] = lrr[r] * al[r] + ss;
            }
            const unsigned any = (__ballot(resc) != 0ull) ? 1u : 0u;
            if (l15 == 0) {
                float4 a4;
                a4.x = al[0]; a4.y = al[1]; a4.z = al[2]; a4.w = al[3];
                *(float4*)(alpha_s + wave * 16 + g * 4) = a4;
            }
            if (lane == 0) flags_s[wave] = any;
        }
        __syncthreads();                       // barrier A: P/alpha/flags visible, QK done
        if (kt + 1 < nk) STAGE_K(kt + 1);      // K-DMA hides under PV
        // ---- O += P V : v-split, wave owns v-cols [128*wave, 128*wave+128) ----
        {
            v8bf vb[8];
#pragma unroll
            for (int n = 0; n < 8; ++n)
                vb[n] = *(const v8bf*)(vt_s + (wave * 128 + n * 16 + l15) * 34 + g * 8);
            const uint4 flg = *(const uint4*)flags_s;
            const unsigned fl[4] = {flg.x, flg.y, flg.z, flg.w};
#pragma unroll
            for (int m = 0; m < 4; ++m) {
                const float4 am = *(const float4*)(alpha_s + m * 16 + g * 4);
                const v8bf pa = *(const v8bf*)(pt_s + (m * 16 + l15) * 34 + g * 8);
                if (fl[m]) {
#pragma unroll
                    for (int n = 0; n < 8; ++n) {
                        acc[m][n][0] *= am.x; acc[m][n][1] *= am.y;
                        acc[m][n][2] *= am.z; acc[m][n][3] *= am.w;
                    }
                }
#pragma unroll
                for (int n = 0; n < 8; ++n)
                    acc[m][n] = __builtin_amdgcn_mfma_f32_16x16x32_bf16(pa, vb[n], acc[m][n], 0, 0, 0);
            }
        }
        if (kt + 1 < nk) {
            __syncthreads();                   // barrier B: all PV reads of vt_s done
            STAGE_V(kt + 1);
            asm volatile("s_waitcnt vmcnt(0)" ::: "memory");
            __syncthreads();                   // barrier C: staged tiles visible
        }
    }
    // ---- normalize + store (lr broadcast) ----
    if (l15 == 0) {
        float4 l4;
        l4.x = lrr[0]; l4.y = lrr[1]; l4.z = lrr[2]; l4.w = lrr[3];
        *(float4*)(lr_s + wave * 16 + g * 4) = l4;
    }
    __syncthreads();
#pragma unroll
    for (int m = 0; m < 4; ++m) {
        const float4 lm = *(const float4*)(lr_s + m * 16 + g * 4);
        const float li0 = 1.f / lm.x, li1 = 1.f / lm.y, li2 = 1.f / lm.z, li3 = 1.f / lm.w;
        u16* op = o_lat + ((size_t)h * T_SEQ + qt0 + m * 16 + g * 4) * 512 + wave * 128 + l15;
#pragma unroll
        for (int n = 0; n < 8; ++n) {
            op[0 * 512 + n * 16] = f2b(acc[m][n][0] * li0);
            op[1 * 512 + n * 16] = f2b(acc[m][n][1] * li1);
            op[2 * 512 + n * 16] = f2b(acc[m][n][2] * li2);
            op[3 * 512 + n * 16] = f2b(acc[m][n][3] * li3);
        }
    }
}

// ---------------------------------------------------------------------------
extern "C" void kernel_launch(void* const* d_in, const int* in_sizes, int n_in,
                              void* d_out, int out_size, void* d_ws, size_t ws_size,
                              hipStream_t stream)
{
    const int*   positions = (const int*)d_in[0];
    const float* hs        = (const float*)d_in[1];
    const float* w_fused   = (const float*)d_in[2];
    const float* w_qb      = (const float*)d_in[3];
    const float* w_kvb     = (const float*)d_in[4];
    const float* w_o       = (const float*)d_in[5];
    const float* qa_w      = (const float*)d_in[6];
    const float* kva_w     = (const float*)d_in[7];
    float* out = (float*)d_out;
    char*  ws  = (char*)d_ws;

    // workspace layout (bytes), phase-disjoint aliasing:
    // R0 (38,010,880): [wfT][wqbT][qanorm] -> later o_lat
    // R1 (17,301,504): qkv f32 -> qn_bf(8.4M)+wkc_bf(2.1M) -> o_mid
    // R2 (25,165,824): hs_bf -> qmat f32 -> woT
    // R3: wvcT | R4: k_img (2,392,064) | R5: v_img (2,228,224) | R6: qfT (37,748,736)
    char* R0 = ws;
    char* R1 = R0 + 38010880;
    char* R2 = R1 + 17301504;
    char* R3 = R2 + 25165824;
    char* R4 = R3 + 2097152;
    char* R5 = R4 + 2392064;
    char* R6 = R5 + 2228224;     // end = R6 + 37,748,736 = 124,944,384 B

    u16*   wfT    = (u16*)R0;
    u16*   wqbT   = (u16*)(R0 + 22282240);
    u16*   qanorm = (u16*)(R0 + 31719424);
    u16*   o_lat  = (u16*)R0;
    float* qkv    = (float*)R1;
    u16*   qn_bf  = (u16*)R1;
    u16*   wkc_bf = (u16*)(R1 + 8388608);
    u16*   o_mid  = (u16*)R1;
    u16*   hs_bf  = (u16*)R2;
    float* qmat   = (float*)R2;
    u16*   woT    = (u16*)R2;
    u16*   wvcT   = (u16*)R3;
    u16*   k_img  = (u16*)R4;
    u16*   v_img  = (u16*)R5;
    u16*   qfT    = (u16*)R6;

    // 1. convert hs -> bf16
    cvt_bf16<<<(T_SEQ * HID / 4 + 255) / 256, 256, 0, stream>>>(hs, hs_bf, T_SEQ * HID / 4);
    // 2. transpose-convert w_fused -> wfT [2112(pad2176)][5120]
    transcvt<<<dim3(HID / 32, QKV_N / 32, 1), 256, 0, stream>>>(w_fused, wfT, QKV_N, 0, 0, 0, HID);
    // 3. qkv = hs @ w_fused   (f32 out)
    gemm_bt<<<dim3((QKV_N + 127) / 128, T_SEQ / 128), 256, 0, stream>>>(
        hs_bf, wfT, qkv, T_SEQ, QKV_N, HID);
    // 4. transpose-convert w_qb -> wqbT [3072][1536]
    transcvt<<<dim3(QL / 32, QB_N / 32, 1), 256, 0, stream>>>(w_qb, wqbT, QB_N, 0, 0, 0, QL);
    // 5. rmsnorms + k_pe rope -> qanorm, k_img, v_img   (qkv dead after this)
    norm_rope_kernel<<<T_SEQ, 256, 0, stream>>>(qkv, qa_w, kva_w, positions, qanorm, k_img, v_img);
    // 6. qmat = qanorm @ w_qb  (f32 out; overwrites hs_bf region)
    gemm_bt<<<dim3(QB_N / 128, T_SEQ / 128), 256, 0, stream>>>(
        qanorm, wqbT, qmat, T_SEQ, QB_N, QL);
    // 7. absorbed q_nope via bf16 MFMA + q_pe rope -> qfT (pre-scaled)
    cast_qnope<<<T_SEQ, 256, 0, stream>>>(qmat, qn_bf);
    cast_wkc<<<1024, 256, 0, stream>>>(w_kvb, wkc_bf);
    gemm_qabs<<<dim3(KVL / 128, T_SEQ / 128, NH), 256, 0, stream>>>(qn_bf, wkc_bf, qfT);
    rope_qpe_kernel<<<T_SEQ, 256, 0, stream>>>(qmat, positions, qfT);
    // 8. wvcT[h][v][l] from w_kvb
    transcvt<<<dim3(KVL / 32, DV / 32, NH), 256, 0, stream>>>(
        w_kvb, wvcT, KVB_N, DN, DN + DV, (long)DV * KVL, KVL);
    // 9. MFMA flash attention v3 -> o_lat bf16 (overwrites wfT/wqbT/qanorm)
    attn_mfma<<<dim3(32, NH), 256, 0, stream>>>(qfT, k_img, v_img, o_lat);
    // 10. o_mid = per-head o_lat @ w_vc  (bf16 out; overwrites qn_bf/wkc_bf)
    gemm_vc<<<dim3(T_SEQ / 128, NH), 256, 0, stream>>>(o_lat, wvcT, o_mid);
    // 11. transpose-convert w_o -> woT [5120][2048] (overwrites qmat)
    transcvt<<<dim3(OD / 32, HID / 32, 1), 256, 0, stream>>>(w_o, woT, HID, 0, 0, 0, OD);
    // 12. out = o_mid @ w_o  (f32 out)
    gemm_bt<<<dim3(HID / 128, T_SEQ / 128), 256, 0, stream>>>(
        o_mid, woT, out, T_SEQ, HID, OD);
}

// Round 7
// 718.257 us; speedup vs baseline: 1.7008x; 1.0886x over previous
//
#include <hip/hip_runtime.h>
#include <math.h>

typedef unsigned short u16;
typedef __bf16 v8bf __attribute__((ext_vector_type(8)));
typedef float   v4f  __attribute__((ext_vector_type(4)));

#define T_SEQ 2048
#define HID   5120
#define NH    16
#define DN    128
#define DR    64
#define DV    128
#define QL    1536
#define KVL   512
#define QKV_N (QL + KVL + DR)    // 2112
#define QB_N  (NH * (DN + DR))   // 3072
#define KVB_N (NH * (DN + DV))   // 4096
#define KFULL (KVL + DR)         // 576
#define OD    (NH * DV)          // 2048
#define SCALE_C 0.07216878364870322f       // (DN+DR)^-0.5
#define ROPE_K  0.28782313662425576f       // ln(10000)/32

// K LDS image: [32 keys][584 u16] (576 valid + 8 pad) = 37,376 B = 2336 x 16B
#define KIMG_U16 18688
// V fragment image (NATURAL key order): [64 kt][32 vblk][4 g][16 l15][8 e] u16
// element = V^T[vdim = vblk*16 + l15][key = g*8 + e]
#define VFRAG_U16 16384

__device__ __forceinline__ u16 f2b(float f) {
    unsigned int u = __float_as_uint(f);
    return (u16)((u + 0x7fffu + ((u >> 16) & 1u)) >> 16);
}

// qfT element index: chunk-major 16-row tiles, fully coalesced fragment loads.
__device__ __forceinline__ size_t qft_idx(int h, int t, int d) {
    return ((((size_t)h * 128 + (t >> 4)) * 72 + (d >> 3)) * 16 + (t & 15)) * 8 + (d & 7);
}

// DPP rotation within each 16-lane row: row_ror:n = 0x120+n
#define ROR_F(x, CTRL) __uint_as_float(__builtin_amdgcn_update_dpp( \
    0, (int)__float_as_uint(x), CTRL, 0xf, 0xf, true))

#if __has_builtin(__builtin_amdgcn_global_load_lds)
#define ASYNC_CP16(gp, lp) __builtin_amdgcn_global_load_lds( \
    (__attribute__((address_space(1))) void*)(gp),           \
    (__attribute__((address_space(3))) void*)(lp), 16, 0, 0)
#else
#define ASYNC_CP16(gp, lp) do { *(uint4*)(lp) = *(const uint4*)(gp); } while (0)
#endif

// ---------------------------------------------------------------------------
// f32 -> bf16 elementwise (n4 = count/4)
// ---------------------------------------------------------------------------
__global__ __launch_bounds__(256) void cvt_bf16(
    const float* __restrict__ in, u16* __restrict__ out, int n4)
{
    int i = blockIdx.x * 256 + threadIdx.x;
    if (i < n4) {
        float4 v = ((const float4*)in)[i];
        ushort4 o;
        o.x = f2b(v.x); o.y = f2b(v.y); o.z = f2b(v.z); o.w = f2b(v.w);
        ((ushort4*)out)[i] = o;
    }
}

// ---------------------------------------------------------------------------
// Transpose+convert: out[n][k] (bf16, row stride Kd) = in[k][col0+z*zcol+n] (f32)
// ---------------------------------------------------------------------------
__global__ __launch_bounds__(256) void transcvt(
    const float* __restrict__ in, u16* __restrict__ out,
    int ldin, int col0, int zcol, long out_z, int Kd)
{
    __shared__ u16 tile[32][33];
    const int bk = blockIdx.x * 32, bn = blockIdx.y * 32, z = blockIdx.z;
    const int r = threadIdx.x >> 3, cg = (threadIdx.x & 7) * 4;
    const float4 v = *(const float4*)(in + (size_t)(bk + r) * ldin + col0 + (size_t)z * zcol + bn + cg);
    tile[r][cg + 0] = f2b(v.x); tile[r][cg + 1] = f2b(v.y);
    tile[r][cg + 2] = f2b(v.z); tile[r][cg + 3] = f2b(v.w);
    __syncthreads();
    ushort4 o;
    o.x = tile[cg + 0][r]; o.y = tile[cg + 1][r];
    o.z = tile[cg + 2][r]; o.w = tile[cg + 3][r];
    *(ushort4*)(out + (size_t)z * out_z + (size_t)(bn + r) * Kd + bk + cg) = o;
}

// ---------------------------------------------------------------------------
// bf16 MFMA GEMM (m97-style): C(f32, MxN) = A(bf16 MxK) * Bt(bf16 NxK)^T
// ---------------------------------------------------------------------------
__global__ __launch_bounds__(256, 2) void gemm_bt(
    const u16* __restrict__ A, const u16* __restrict__ Bt,
    float* __restrict__ C, int M, int N, int K)
{
    __shared__ u16 As[128 * 32], Bs[128 * 32];
    const int tid = threadIdx.x, lane = tid & 63, wave = tid >> 6;
    const int g = lane >> 4, l15 = lane & 15;
    const int bm = blockIdx.y * 128, bn = blockIdx.x * 128;
    const int wm = (wave & 1) * 64, wn = (wave >> 1) * 64;
    const int srow = tid >> 2, skq = (tid & 3) * 8;
    v4f acc[4][4];
#pragma unroll
    for (int i = 0; i < 4; ++i)
#pragma unroll
        for (int j = 0; j < 4; ++j) acc[i][j] = (v4f){0.f, 0.f, 0.f, 0.f};

    for (int k0 = 0; k0 < K; k0 += 32) {
        ASYNC_CP16(A  + (size_t)(bm + srow) * K + k0 + skq,      &As[tid * 8]);
        ASYNC_CP16(A  + (size_t)(bm + 64 + srow) * K + k0 + skq, &As[2048 + tid * 8]);
        ASYNC_CP16(Bt + (size_t)(bn + srow) * K + k0 + skq,      &Bs[tid * 8]);
        ASYNC_CP16(Bt + (size_t)(bn + 64 + srow) * K + k0 + skq, &Bs[2048 + tid * 8]);
        __syncthreads();
        v8bf af[4], bq[4];
#pragma unroll
        for (int mi = 0; mi < 4; ++mi) af[mi] = *(const v8bf*)&As[(wm + mi * 16 + l15) * 32 + g * 8];
#pragma unroll
        for (int ni = 0; ni < 4; ++ni) bq[ni] = *(const v8bf*)&Bs[(wn + ni * 16 + l15) * 32 + g * 8];
#pragma unroll
        for (int mi = 0; mi < 4; ++mi)
#pragma unroll
            for (int ni = 0; ni < 4; ++ni)
                acc[mi][ni] = __builtin_amdgcn_mfma_f32_16x16x32_bf16(af[mi], bq[ni], acc[mi][ni], 0, 0, 0);
        __syncthreads();
    }
#pragma unroll
    for (int mi = 0; mi < 4; ++mi)
#pragma unroll
        for (int ni = 0; ni < 4; ++ni) {
            const int col = bn + wn + ni * 16 + l15;
            if (col < N) {
#pragma unroll
                for (int r = 0; r < 4; ++r)
                    C[(size_t)(bm + wm + mi * 16 + g * 4 + r) * N + col] = acc[mi][ni][r];
            }
        }
}

// ---------------------------------------------------------------------------
// Batched per-head w_vc GEMM: o_mid[t][h*128+v] = o_lat_h(2048x512) @ wvcT_h(128x512)^T
// ---------------------------------------------------------------------------
__global__ __launch_bounds__(256, 2) void gemm_vc(
    const u16* __restrict__ o_lat, const u16* __restrict__ wvcT,
    u16* __restrict__ o_mid)
{
    __shared__ u16 As[128 * 32], Bs[128 * 32];
    const int tid = threadIdx.x, lane = tid & 63, wave = tid >> 6;
    const int g = lane >> 4, l15 = lane & 15;
    const int h = blockIdx.y;
    const int bm = blockIdx.x * 128;
    const u16* A  = o_lat + (size_t)h * T_SEQ * 512;
    const u16* Bt = wvcT + (size_t)h * 128 * 512;
    const int wm = (wave & 1) * 64, wn = (wave >> 1) * 64;
    const int srow = tid >> 2, skq = (tid & 3) * 8;
    v4f acc[4][4];
#pragma unroll
    for (int i = 0; i < 4; ++i)
#pragma unroll
        for (int j = 0; j < 4; ++j) acc[i][j] = (v4f){0.f, 0.f, 0.f, 0.f};

    for (int k0 = 0; k0 < 512; k0 += 32) {
        ASYNC_CP16(A  + (size_t)(bm + srow) * 512 + k0 + skq,      &As[tid * 8]);
        ASYNC_CP16(A  + (size_t)(bm + 64 + srow) * 512 + k0 + skq, &As[2048 + tid * 8]);
        ASYNC_CP16(Bt + (size_t)(srow) * 512 + k0 + skq,           &Bs[tid * 8]);
        ASYNC_CP16(Bt + (size_t)(64 + srow) * 512 + k0 + skq,      &Bs[2048 + tid * 8]);
        __syncthreads();
        v8bf af[4], bq[4];
#pragma unroll
        for (int mi = 0; mi < 4; ++mi) af[mi] = *(const v8bf*)&As[(wm + mi * 16 + l15) * 32 + g * 8];
#pragma unroll
        for (int ni = 0; ni < 4; ++ni) bq[ni] = *(const v8bf*)&Bs[(wn + ni * 16 + l15) * 32 + g * 8];
#pragma unroll
        for (int mi = 0; mi < 4; ++mi)
#pragma unroll
            for (int ni = 0; ni < 4; ++ni)
                acc[mi][ni] = __builtin_amdgcn_mfma_f32_16x16x32_bf16(af[mi], bq[ni], acc[mi][ni], 0, 0, 0);
        __syncthreads();
    }
#pragma unroll
    for (int mi = 0; mi < 4; ++mi)
#pragma unroll
        for (int ni = 0; ni < 4; ++ni)
#pragma unroll
            for (int r = 0; r < 4; ++r)
                o_mid[(size_t)(bm + wm + mi * 16 + g * 4 + r) * OD + h * 128 + wn + ni * 16 + l15] =
                    f2b(acc[mi][ni][r]);
}

// ---------------------------------------------------------------------------
// Fused rmsnorms + k_pe rope. Writes qanorm bf16, k_img (K LDS image) and
// v_frag (V in per-wave MFMA fragment order, NATURAL key order:
// key c -> g = c>>3, e = c&7).
// ---------------------------------------------------------------------------
__global__ __launch_bounds__(256) void norm_rope_kernel(
    const float* __restrict__ qkv, const float* __restrict__ qa_w,
    const float* __restrict__ kva_w, const int* __restrict__ positions,
    u16* __restrict__ qanorm, u16* __restrict__ k_img, u16* __restrict__ v_frag)
{
    const int t = blockIdx.x, tid = threadIdx.x;
    const float* row = qkv + (size_t)t * QKV_N;
    float sq = 0.f, skv = 0.f;
    for (int i = tid; i < QL; i += 256)  { const float v = row[i];      sq  = fmaf(v, v, sq); }
    for (int i = tid; i < KVL; i += 256) { const float v = row[QL + i]; skv = fmaf(v, v, skv); }
#pragma unroll
    for (int off = 32; off >= 1; off >>= 1) {
        sq  += __shfl_down(sq, off, 64);
        skv += __shfl_down(skv, off, 64);
    }
    __shared__ float red[2][4];
    __shared__ float rs[2];
    const int wv = tid >> 6;
    if ((tid & 63) == 0) { red[0][wv] = sq; red[1][wv] = skv; }
    __syncthreads();
    if (tid == 0) {
        const float a = red[0][0] + red[0][1] + red[0][2] + red[0][3];
        const float b = red[1][0] + red[1][1] + red[1][2] + red[1][3];
        rs[0] = rsqrtf(a / (float)QL + 1e-6f);
        rs[1] = rsqrtf(b / (float)KVL + 1e-6f);
    }
    __syncthreads();
    const float rq = rs[0], rkv = rs[1];
    for (int i = tid; i < QL; i += 256)
        qanorm[(size_t)t * QL + i] = f2b(row[i] * rq * qa_w[i]);
    const int kt = t >> 5, c = t & 31;
    u16* krow = k_img + (size_t)kt * KIMG_U16 + (size_t)c * 584;
    u16* vbase = v_frag + (size_t)kt * VFRAG_U16 + (c >> 3) * 128 + (c & 7);
    for (int i = tid; i < KVL; i += 256) {
        const u16 b = f2b(row[QL + i] * rkv * kva_w[i]);
        krow[i] = b;
        // fragment element: [vblk = i>>4][g = c>>3][l15 = i&15][e = c&7]
        vbase[(size_t)(i >> 4) * 512 + (size_t)(i & 15) * 8] = b;
    }
    if (tid < 32) {
        const float pos = (float)positions[t];
        const float inv = __expf(-(float)tid * ROPE_K);
        float s, cc;
        __sincosf(pos * inv, &s, &cc);
        const float x1 = row[QL + KVL + 2 * tid];
        const float x2 = row[QL + KVL + 2 * tid + 1];
        krow[KVL + 2 * tid]     = f2b(x1 * cc - x2 * s);
        krow[KVL + 2 * tid + 1] = f2b(x2 * cc + x1 * s);
    }
}

// ---------------------------------------------------------------------------
// Fused: cast qmat q_nope slices -> qn_bf bf16, and RoPE q_pe -> qfT[512:576].
// ---------------------------------------------------------------------------
__global__ __launch_bounds__(256) void cast_rope(
    const float* __restrict__ qmat, const int* __restrict__ positions,
    u16* __restrict__ qn_bf, u16* __restrict__ qfT)
{
    const int t = blockIdx.x, tid = threadIdx.x;
#pragma unroll
    for (int i = 0; i < 2; ++i) {
        const int p4 = (tid + i * 256) * 4;          // 0..2044
        const int h = p4 >> 7, d = p4 & 127;
        const float4 v = *(const float4*)(qmat + (size_t)t * QB_N + h * (DN + DR) + d);
        ushort4 o;
        o.x = f2b(v.x); o.y = f2b(v.y); o.z = f2b(v.z); o.w = f2b(v.w);
        *(ushort4*)(qn_bf + ((size_t)h * T_SEQ + t) * DN + d) = o;
    }
    const float pos = (float)positions[t];
    for (int p = tid; p < NH * 32; p += 256) {
        const int h = p >> 5, i = p & 31;
        const float inv = __expf(-(float)i * ROPE_K);
        float s, c;
        __sincosf(pos * inv, &s, &c);
        const float* src = qmat + (size_t)t * QB_N + h * (DN + DR) + DN;
        const float x1 = src[2 * i], x2 = src[2 * i + 1];
        qfT[qft_idx(h, t, KVL + 2 * i)]     = f2b(SCALE_C * (x1 * c - x2 * s));
        qfT[qft_idx(h, t, KVL + 2 * i + 1)] = f2b(SCALE_C * (x2 * c + x1 * s));
    }
}

// ---------------------------------------------------------------------------
// Cast w_kvb kc slices -> wkc_bf[h][l][128] bf16
// ---------------------------------------------------------------------------
__global__ __launch_bounds__(256) void cast_wkc(
    const float* __restrict__ w_kvb, u16* __restrict__ wkc_bf)
{
    const int gid = blockIdx.x * 256 + threadIdx.x;
    const int p4 = gid * 4;
    const int h = p4 >> 16, rem = p4 & 65535, l = rem >> 7, d = rem & 127;
    const float4 v = *(const float4*)(w_kvb + (size_t)l * KVB_N + h * (DN + DV) + d);
    ushort4 o;
    o.x = f2b(v.x); o.y = f2b(v.y); o.z = f2b(v.z); o.w = f2b(v.w);
    *(ushort4*)(wkc_bf + (size_t)p4) = o;
}

// ---------------------------------------------------------------------------
// Absorbed q_nope via bf16 MFMA per head: qfT[h][t][l<512] = scale * qn_h @ wkc_h^T
// ---------------------------------------------------------------------------
__global__ __launch_bounds__(256, 2) void gemm_qabs(
    const u16* __restrict__ qn_bf, const u16* __restrict__ wkc_bf,
    u16* __restrict__ qfT)
{
    __shared__ u16 As[128 * 32], Bs[128 * 32];
    const int tid = threadIdx.x, lane = tid & 63, wave = tid >> 6;
    const int g = lane >> 4, l15 = lane & 15;
    const int h = blockIdx.z;
    const int bm = blockIdx.y * 128, bn = blockIdx.x * 128;
    const u16* A  = qn_bf + (size_t)h * T_SEQ * DN;
    const u16* Bt = wkc_bf + (size_t)h * KVL * DN;
    const int wm = (wave & 1) * 64, wn = (wave >> 1) * 64;
    const int srow = tid >> 2, skq = (tid & 3) * 8;
    v4f acc[4][4];
#pragma unroll
    for (int i = 0; i < 4; ++i)
#pragma unroll
        for (int j = 0; j < 4; ++j) acc[i][j] = (v4f){0.f, 0.f, 0.f, 0.f};

    for (int k0 = 0; k0 < DN; k0 += 32) {
        ASYNC_CP16(A  + (size_t)(bm + srow) * DN + k0 + skq,      &As[tid * 8]);
        ASYNC_CP16(A  + (size_t)(bm + 64 + srow) * DN + k0 + skq, &As[2048 + tid * 8]);
        ASYNC_CP16(Bt + (size_t)(bn + srow) * DN + k0 + skq,      &Bs[tid * 8]);
        ASYNC_CP16(Bt + (size_t)(bn + 64 + srow) * DN + k0 + skq, &Bs[2048 + tid * 8]);
        __syncthreads();
        v8bf af[4], bq[4];
#pragma unroll
        for (int mi = 0; mi < 4; ++mi) af[mi] = *(const v8bf*)&As[(wm + mi * 16 + l15) * 32 + g * 8];
#pragma unroll
        for (int ni = 0; ni < 4; ++ni) bq[ni] = *(const v8bf*)&Bs[(wn + ni * 16 + l15) * 32 + g * 8];
#pragma unroll
        for (int mi = 0; mi < 4; ++mi)
#pragma unroll
            for (int ni = 0; ni < 4; ++ni)
                acc[mi][ni] = __builtin_amdgcn_mfma_f32_16x16x32_bf16(af[mi], bq[ni], acc[mi][ni], 0, 0, 0);
        __syncthreads();
    }
#pragma unroll
    for (int mi = 0; mi < 4; ++mi)
#pragma unroll
        for (int ni = 0; ni < 4; ++ni)
#pragma unroll
            for (int r = 0; r < 4; ++r) {
                const int t = bm + wm + mi * 16 + g * 4 + r;
                const int d = bn + wn + ni * 16 + l15;
                qfT[qft_idx(h, t, d)] = f2b(acc[mi][ni][r] * SCALE_C);
            }
}

// ---------------------------------------------------------------------------
// MFMA flash attention v5 (= r5-proven data flow, V moved to global).
// 512 blocks (balanced bijective map), 4 waves. QK row-split, 4 accumulators.
// Softmax: DPP row_ror reduce; P stored as TWO u16 stores in NATURAL key
// order (r5-proven pattern). PV v-split; V fragments loaded from v_frag
// global (natural key order, coalesced) into registers — no V LDS/DMA.
// Per iter: QK -> vb loads -> softmax -> B-A -> STAGE_K(kt+1) -> PV ->
// vmcnt(0) -> B-B. Two barriers; K-DMA covered by PV.
// ---------------------------------------------------------------------------
__global__ __launch_bounds__(256, 2) void attn_mfma(
    const u16* __restrict__ qfT, const u16* __restrict__ k_img,
    const u16* __restrict__ v_frag, u16* __restrict__ o_lat)
{
    __shared__ u16 ks_s[32 * 584];               // 37,376 B
    __shared__ u16 pt_s[64 * 34];                //  4,352 B
    __shared__ __align__(16) float alpha_s[64];
    __shared__ __align__(16) float lr_s[64];
    __shared__ __align__(16) unsigned flags_s[4];
    const int h = blockIdx.y;
    const int s = (((blockIdx.x >> 1) + 5 * h) & 15);
    const int tile = (blockIdx.x & 1) ? (31 - s) : s;
    const int qt0 = tile * 64;
    const int nk = 2 * tile + 2;
    const int tid = threadIdx.x, lane = tid & 63, wave = tid >> 6;
    const int g = lane >> 4, l15 = lane & 15;

    const u16* qp = qfT + (size_t)(h * 128 + (qt0 >> 4) + wave) * 9216 + g * 128 + l15 * 8;

    auto STAGE_K = [&](int kt) {
        const char* src = (const char*)(k_img + (size_t)kt * KIMG_U16);
        char* dst = (char*)ks_s;
#pragma unroll
        for (int i = 0; i < 9; ++i)
            ASYNC_CP16(src + (tid + i * 256) * 16, dst + (tid + i * 256) * 16);
        if (tid < 32)
            ASYNC_CP16(src + (2304 + tid) * 16, dst + (2304 + tid) * 16);
    };

    v4f acc[4][8];
#pragma unroll
    for (int m = 0; m < 4; ++m)
#pragma unroll
        for (int n = 0; n < 8; ++n) acc[m][n] = (v4f){0.f, 0.f, 0.f, 0.f};
    float mr[4] = {-1e30f, -1e30f, -1e30f, -1e30f};
    float lrr[4] = {0.f, 0.f, 0.f, 0.f};

    STAGE_K(0);
    asm volatile("s_waitcnt vmcnt(0)" ::: "memory");
    __syncthreads();

    for (int kt = 0; kt < nk; ++kt) {
        const int kt0 = kt * 32;
        // ---- S = Q K^T, 4 accumulators (halved dep chain) ----
        v4f s0a = (v4f){0.f, 0.f, 0.f, 0.f}, s0b = s0a, s1a = s0a, s1b = s0a;
        __builtin_amdgcn_s_setprio(1);
#pragma unroll
        for (int half = 0; half < 2; ++half) {
            v8bf aq[9];
#pragma unroll
            for (int c = 0; c < 9; ++c)
                aq[c] = *(const v8bf*)(qp + (half * 9 + c) * 512);
#pragma unroll
            for (int c = 0; c < 9; ++c) {
                const int o = (half * 9 + c) * 32 + g * 8;
                const v8bf b0 = *(const v8bf*)(ks_s + l15 * 584 + o);
                const v8bf b1 = *(const v8bf*)(ks_s + (16 + l15) * 584 + o);
                if (half == 0) {
                    s0a = __builtin_amdgcn_mfma_f32_16x16x32_bf16(aq[c], b0, s0a, 0, 0, 0);
                    s1a = __builtin_amdgcn_mfma_f32_16x16x32_bf16(aq[c], b1, s1a, 0, 0, 0);
                } else {
                    s0b = __builtin_amdgcn_mfma_f32_16x16x32_bf16(aq[c], b0, s0b, 0, 0, 0);
                    s1b = __builtin_amdgcn_mfma_f32_16x16x32_bf16(aq[c], b1, s1b, 0, 0, 0);
                }
            }
        }
        __builtin_amdgcn_s_setprio(0);
        // ---- V fragments for THIS tile: coalesced global -> regs ----
        v8bf vb[8];
        {
            const u16* vf = v_frag + (size_t)(kt * 32 + wave * 8) * 512 + lane * 8;
#pragma unroll
            for (int n = 0; n < 8; ++n) vb[n] = *(const v8bf*)(vf + n * 512);
        }
        // ---- online softmax (DPP reduce); natural-order u16 P stores ----
        {
            const int qr = qt0 + wave * 16 + g * 4;
            const int kc0 = kt0 + l15, kc1 = kt0 + 16 + l15;
            float al[4];
            unsigned resc = 0;
#pragma unroll
            for (int r = 0; r < 4; ++r) {
                const float sv0 = (kc0 <= qr + r) ? (s0a[r] + s0b[r]) : -1e30f;
                const float sv1 = (kc1 <= qr + r) ? (s1a[r] + s1b[r]) : -1e30f;
                float v = fmaxf(sv0, sv1);
                v = fmaxf(v, ROR_F(v, 0x128));
                v = fmaxf(v, ROR_F(v, 0x124));
                v = fmaxf(v, ROR_F(v, 0x122));
                v = fmaxf(v, ROR_F(v, 0x121));
                const float mx = fmaxf(mr[r], v);
                al[r] = __expf(mr[r] - mx);
                resc |= (mx != mr[r]) ? 1u : 0u;
                const float p0 = __expf(sv0 - mx);
                const float p1 = __expf(sv1 - mx);
                pt_s[(wave * 16 + g * 4 + r) * 34 + l15]      = f2b(p0);
                pt_s[(wave * 16 + g * 4 + r) * 34 + 16 + l15] = f2b(p1);
                float ss = p0 + p1;
                ss += ROR_F(ss, 0x128);
                ss += ROR_F(ss, 0x124);
                ss += ROR_F(ss, 0x122);
                ss += ROR_F(ss, 0x121);
                mr[r] = mx;
                lrr[r] = lrr[r] * al[r] + ss;
            }
            const unsigned any = (__ballot(resc) != 0ull) ? 1u : 0u;
            if (l15 == 0) {
                float4 a4;
                a4.x = al[0]; a4.y = al[1]; a4.z = al[2]; a4.w = al[3];
                *(float4*)(alpha_s + wave * 16 + g * 4) = a4;
            }
            if (lane == 0) flags_s[wave] = any;
        }
        __syncthreads();                       // B-A: ks_s reads done; P/alpha/flags visible
        if (kt + 1 < nk) STAGE_K(kt + 1);      // K DMA hidden under PV
        // ---- O += P V : v-split, V from registers ----
        {
            const uint4 flg = *(const uint4*)flags_s;
            const unsigned fl[4] = {flg.x, flg.y, flg.z, flg.w};
            __builtin_amdgcn_s_setprio(1);
#pragma unroll
            for (int m = 0; m < 4; ++m) {
                const float4 am = *(const float4*)(alpha_s + m * 16 + g * 4);
                const v8bf pa = *(const v8bf*)(pt_s + (m * 16 + l15) * 34 + g * 8);
                if (fl[m]) {
#pragma unroll
                    for (int n = 0; n < 8; ++n) {
                        acc[m][n][0] *= am.x; acc[m][n][1] *= am.y;
                        acc[m][n][2] *= am.z; acc[m][n][3] *= am.w;
                    }
                }
#pragma unroll
                for (int n = 0; n < 8; ++n)
                    acc[m][n] = __builtin_amdgcn_mfma_f32_16x16x32_bf16(pa, vb[n], acc[m][n], 0, 0, 0);
            }
            __builtin_amdgcn_s_setprio(0);
        }
        if (kt + 1 < nk) {
            asm volatile("s_waitcnt vmcnt(0)" ::: "memory");   // K DMA landed (covered by PV)
            __syncthreads();                   // B-B: staged K visible
        }
    }
    // ---- normalize + store (lr broadcast) ----
    if (l15 == 0) {
        float4 l4;
        l4.x = lrr[0]; l4.y = lrr[1]; l4.z = lrr[2]; l4.w = lrr[3];
        *(float4*)(lr_s + wave * 16 + g * 4) = l4;
    }
    __syncthreads();
#pragma unroll
    for (int m = 0; m < 4; ++m) {
        const float4 lm = *(const float4*)(lr_s + m * 16 + g * 4);
        const float li0 = 1.f / lm.x, li1 = 1.f / lm.y, li2 = 1.f / lm.z, li3 = 1.f / lm.w;
        u16* op = o_lat + ((size_t)h * T_SEQ + qt0 + m * 16 + g * 4) * 512 + wave * 128 + l15;
#pragma unroll
        for (int n = 0; n < 8; ++n) {
            op[0 * 512 + n * 16] = f2b(acc[m][n][0] * li0);
            op[1 * 512 + n * 16] = f2b(acc[m][n][1] * li1);
            op[2 * 512 + n * 16] = f2b(acc[m][n][2] * li2);
            op[3 * 512 + n * 16] = f2b(acc[m][n][3] * li3);
        }
    }
}

// ---------------------------------------------------------------------------
extern "C" void kernel_launch(void* const* d_in, const int* in_sizes, int n_in,
                              void* d_out, int out_size, void* d_ws, size_t ws_size,
                              hipStream_t stream)
{
    const int*   positions = (const int*)d_in[0];
    const float* hs        = (const float*)d_in[1];
    const float* w_fused   = (const float*)d_in[2];
    const float* w_qb      = (const float*)d_in[3];
    const float* w_kvb     = (const float*)d_in[4];
    const float* w_o       = (const float*)d_in[5];
    const float* qa_w      = (const float*)d_in[6];
    const float* kva_w     = (const float*)d_in[7];
    float* out = (float*)d_out;
    char*  ws  = (char*)d_ws;

    // workspace layout (bytes), phase-disjoint aliasing:
    // R0 (38,010,880): [wfT][wqbT][qanorm] -> later o_lat
    // R1 (17,301,504): qkv f32 -> qn_bf(8.4M)+wkc_bf(2.1M) -> o_mid
    // R2 (25,165,824): hs_bf -> qmat f32 -> woT
    // R3: wvcT | R4: k_img (2,392,064) | R5: v_frag (2,097,152) | R6: qfT (37,748,736)
    char* R0 = ws;
    char* R1 = R0 + 38010880;
    char* R2 = R1 + 17301504;
    char* R3 = R2 + 25165824;
    char* R4 = R3 + 2097152;
    char* R5 = R4 + 2392064;
    char* R6 = R5 + 2097152;     // end = R6 + 37,748,736 = 124,813,312 B

    u16*   wfT    = (u16*)R0;
    u16*   wqbT   = (u16*)(R0 + 22282240);
    u16*   qanorm = (u16*)(R0 + 31719424);
    u16*   o_lat  = (u16*)R0;
    float* qkv    = (float*)R1;
    u16*   qn_bf  = (u16*)R1;
    u16*   wkc_bf = (u16*)(R1 + 8388608);
    u16*   o_mid  = (u16*)R1;
    u16*   hs_bf  = (u16*)R2;
    float* qmat   = (float*)R2;
    u16*   woT    = (u16*)R2;
    u16*   wvcT   = (u16*)R3;
    u16*   k_img  = (u16*)R4;
    u16*   v_frag = (u16*)R5;
    u16*   qfT    = (u16*)R6;

    // 1. convert hs -> bf16
    cvt_bf16<<<(T_SEQ * HID / 4 + 255) / 256, 256, 0, stream>>>(hs, hs_bf, T_SEQ * HID / 4);
    // 2. transpose-convert w_fused -> wfT [2112(pad2176)][5120]
    transcvt<<<dim3(HID / 32, QKV_N / 32, 1), 256, 0, stream>>>(w_fused, wfT, QKV_N, 0, 0, 0, HID);
    // 3. qkv = hs @ w_fused   (f32 out)
    gemm_bt<<<dim3((QKV_N + 127) / 128, T_SEQ / 128), 256, 0, stream>>>(
        hs_bf, wfT, qkv, T_SEQ, QKV_N, HID);
    // 4. transpose-convert w_qb -> wqbT [3072][1536]
    transcvt<<<dim3(QL / 32, QB_N / 32, 1), 256, 0, stream>>>(w_qb, wqbT, QB_N, 0, 0, 0, QL);
    // 5. rmsnorms + k_pe rope -> qanorm, k_img, v_frag   (qkv dead after this)
    norm_rope_kernel<<<T_SEQ, 256, 0, stream>>>(qkv, qa_w, kva_w, positions, qanorm, k_img, v_frag);
    // 6. qmat = qanorm @ w_qb  (f32 out; overwrites hs_bf region)
    gemm_bt<<<dim3(QB_N / 128, T_SEQ / 128), 256, 0, stream>>>(
        qanorm, wqbT, qmat, T_SEQ, QB_N, QL);
    // 7. absorbed q_nope via bf16 MFMA + q_pe rope -> qfT (pre-scaled)
    cast_rope<<<T_SEQ, 256, 0, stream>>>(qmat, positions, qn_bf, qfT);
    cast_wkc<<<1024, 256, 0, stream>>>(w_kvb, wkc_bf);
    gemm_qabs<<<dim3(KVL / 128, T_SEQ / 128, NH), 256, 0, stream>>>(qn_bf, wkc_bf, qfT);
    // 8. wvcT[h][v][l] from w_kvb
    transcvt<<<dim3(KVL / 32, DV / 32, NH), 256, 0, stream>>>(
        w_kvb, wvcT, KVB_N, DN, DN + DV, (long)DV * KVL, KVL);
    // 9. MFMA flash attention v5 -> o_lat bf16 (overwrites wfT/wqbT/qanorm)
    attn_mfma<<<dim3(32, NH), 256, 0, stream>>>(qfT, k_img, v_frag, o_lat);
    // 10. o_mid = per-head o_lat @ w_vc  (bf16 out; overwrites qn_bf/wkc_bf)
    gemm_vc<<<dim3(T_SEQ / 128, NH), 256, 0, stream>>>(o_lat, wvcT, o_mid);
    // 11. transpose-convert w_o -> woT [5120][2048] (overwrites qmat)
    transcvt<<<dim3(OD / 32, HID / 32, 1), 256, 0, stream>>>(w_o, woT, HID, 0, 0, 0, OD);
    // 12. out = o_mid @ w_o  (f32 out)
    gemm_bt<<<dim3(HID / 128, T_SEQ / 128), 256, 0, stream>>>(
        o_mid, woT, out, T_SEQ, HID, OD);
}